// Round 5
// baseline (1648.957 us; speedup 1.0000x reference)
//
#include <hip/hip_runtime.h>

#define BN_SCALE 0.9999950000374997f  // 1/sqrt(1+1e-5)

// ---- DPP full-wave reductions (validated in fps/knn since R2/R4) ----
template <int CTRL>
__device__ __forceinline__ float dpp_fmax_step(float v) {
  int xi = __builtin_bit_cast(int, v);
  int ti = __builtin_amdgcn_update_dpp(xi, xi, CTRL, 0xf, 0xf, false);  // invalid lanes -> old(=v)
  return fmaxf(v, __builtin_bit_cast(float, ti));
}
template <int CTRL>
__device__ __forceinline__ int dpp_imin_step(int v) {
  int t = __builtin_amdgcn_update_dpp(v, v, CTRL, 0xf, 0xf, false);    // invalid lanes -> old(=v)
  return (t < v) ? t : v;
}
__device__ __forceinline__ float wave_fmax(float v) {
  v = dpp_fmax_step<0x111>(v);  // row_shr:1
  v = dpp_fmax_step<0x112>(v);  // row_shr:2
  v = dpp_fmax_step<0x114>(v);  // row_shr:4
  v = dpp_fmax_step<0x118>(v);  // row_shr:8
  v = dpp_fmax_step<0x142>(v);  // row_bcast:15
  v = dpp_fmax_step<0x143>(v);  // row_bcast:31
  return __builtin_bit_cast(float, __builtin_amdgcn_readlane(__builtin_bit_cast(int, v), 63));
}
__device__ __forceinline__ int wave_imin(int v) {
  v = dpp_imin_step<0x111>(v);
  v = dpp_imin_step<0x112>(v);
  v = dpp_imin_step<0x114>(v);
  v = dpp_imin_step<0x118>(v);
  v = dpp_imin_step<0x142>(v);
  v = dpp_imin_step<0x143>(v);
  return __builtin_amdgcn_readlane(v, 63);
}

// ---------------- knn4: 4 queries/block (R4 version, unchanged) ----------------
template <int R>
__global__ void knn4_kernel(const float* __restrict__ Q, int qStrideB,
                            const float* __restrict__ Xc, int cStrideB,
                            int C, int M, int N, int k, int* __restrict__ idxOut) {
  constexpr int NR = 4 * R;                          // values per lane in selection
  __shared__ float negd[4][R * 256];
  int b = blockIdx.y, q0 = blockIdx.x * 4, tid = threadIdx.x;
  const float* qb = Q + (long)b * qStrideB + q0;     // + c*M walks channels (uniform)
  const float* cb = Xc + (long)b * cStrideB;         // uniform
  float d0[R], d1[R], d2[R], d3[R], sq[R];
  #pragma unroll
  for (int i = 0; i < R; ++i) { d0[i] = d1[i] = d2[i] = d3[i] = sq[i] = 0.f; }
  for (int c = 0; c < C; ++c) {
    float4 q4 = *(const float4*)(qb + (long)c * M);  // uniform -> scalar load
    const float* pc = cb + (long)c * N;              // uniform base
    #pragma unroll
    for (int i = 0; i < R; ++i) {
      float xv = pc[tid + 256 * i];
      sq[i] = fmaf(xv, xv, sq[i]);
      d0[i] = fmaf(q4.x, xv, d0[i]);
      d1[i] = fmaf(q4.y, xv, d1[i]);
      d2[i] = fmaf(q4.z, xv, d2[i]);
      d3[i] = fmaf(q4.w, xv, d3[i]);
    }
  }
  #pragma unroll
  for (int i = 0; i < R; ++i) {
    int m = tid + 256 * i;
    negd[0][m] = 2.f * d0[i] - sq[i];
    negd[1][m] = 2.f * d1[i] - sq[i];
    negd[2][m] = 2.f * d2[i] - sq[i];
    negd[3][m] = 2.f * d3[i] - sq[i];
  }
  __syncthreads();
  int lane = tid & 63, w = tid >> 6;
  const float* row = negd[w];
  int* outp = idxOut + ((long)b * M + (q0 + w)) * k;
  float v[NR];
  #pragma unroll
  for (int i = 0; i < NR; ++i) v[i] = row[lane + 64 * i];   // conflict-free, once
  for (int kk = 0; kk < k; ++kk) {
    float best = -INFINITY; int ib = 0;
    #pragma unroll
    for (int i = 0; i < NR; ++i) {
      bool c = v[i] > best;                 // strict > : first (smallest m) kept on ties
      best = c ? v[i] : best;
      ib = c ? i : ib;
    }
    int bi = (best > -INFINITY) ? (lane + (ib << 6)) : N;   // all-removed lane -> N (orig sem)
    float gmax = wave_fmax(best);
    int cand = (best == gmax) ? bi : 0x7FFFFFFF;
    int big = wave_imin(cand);              // smallest index among global maxima (uniform)
    if (lane == 0) outp[kk] = big;
    int ri = big >> 6;                      // uniform
    bool mine = (lane == (big & 63));
    #pragma unroll
    for (int i = 0; i < NR; ++i)
      if (i == ri) v[i] = mine ? -INFINITY : v[i];          // i==ri uniform -> 1 cndmask
  }
}

// ---------------- gemmPS: one pass computes BOTH halves of the edge-conv weight ----------------
__global__ void gemmPS_kernel(const float* __restrict__ X, int xStrideB, int C, int Np,
                              const float* __restrict__ W, int ldw, int O,
                              float* __restrict__ PtT, float* __restrict__ StT) {
  __shared__ float Wp[16][65];
  __shared__ float Ws[16][65];
  __shared__ float Xt[16][65];
  int b = blockIdx.z;
  int n0 = blockIdx.x * 64, o0 = blockIdx.y * 64;
  int tid = threadIdx.x;
  int to = tid % 16, tn = tid / 16;
  float accP[4][4] = {}, accS[4][4] = {};
  for (int c0 = 0; c0 < C; c0 += 16) {
    for (int e = tid; e < 16 * 64; e += 256) {
      int oo = e / 16, kk = e % 16;
      int c = c0 + kk, o = o0 + oo;
      bool ok = (c < C && o < O);
      Wp[kk][oo] = ok ? W[(long)o * ldw + c] : 0.f;
      Ws[kk][oo] = ok ? W[(long)o * ldw + C + c] : 0.f;
    }
    for (int e = tid; e < 16 * 64; e += 256) {
      int kk = e / 64, nn = e % 64;
      int c = c0 + kk, n = n0 + nn;
      Xt[kk][nn] = (c < C && n < Np) ? X[(long)b * xStrideB + (long)c * Np + n] : 0.f;
    }
    __syncthreads();
    for (int kk = 0; kk < 16; ++kk) {
      float xv[4], wp[4], ws[4];
      for (int i = 0; i < 4; ++i) xv[i] = Xt[kk][tn + 16 * i];
      for (int j = 0; j < 4; ++j) { wp[j] = Wp[kk][to + 16 * j]; ws[j] = Ws[kk][to + 16 * j]; }
      for (int i = 0; i < 4; ++i)
        for (int j = 0; j < 4; ++j) {
          accP[i][j] = fmaf(xv[i], wp[j], accP[i][j]);
          accS[i][j] = fmaf(xv[i], ws[j], accS[i][j]);
        }
    }
    __syncthreads();
  }
  for (int i = 0; i < 4; ++i) {
    int n = n0 + tn + 16 * i;
    if (n >= Np) continue;
    for (int j = 0; j < 4; ++j) {
      int o = o0 + to + 16 * j;
      if (o < O) {
        long off = ((long)b * Np + n) * O + o;
        PtT[off] = accP[i][j];
        StT[off] = accS[i][j];
      }
    }
  }
}

// ---------------- ecfinish ----------------
__global__ void ecfinish_kernel(const float* __restrict__ Pt, const float* __restrict__ St,
                                const int* __restrict__ idx, int k, int O, int Np,
                                const float* __restrict__ g, const float* __restrict__ bb,
                                float* __restrict__ outp, long oStrideB) {
  int b = blockIdx.y;
  int n = blockIdx.x * blockDim.y + threadIdx.y;
  int o = threadIdx.x;
  const float* PtB = Pt + (long)b * Np * O;
  const float* StB = St + (long)b * Np * O;
  const int* ip = idx + ((long)b * Np + n) * k;
  float mx = -INFINITY, mn = INFINITY;
  for (int kk = 0; kk < k; ++kk) {
    float v = PtB[(long)ip[kk] * O + o];
    mx = fmaxf(mx, v); mn = fminf(mn, v);
  }
  float ctrP = PtB[(long)n * O + o];
  float ctrS = StB[(long)n * O + o];
  float gs = g[o] * BN_SCALE;
  float m = (gs >= 0.f) ? mx : mn;
  float h = (ctrS - ctrP + m) * gs + bb[o];
  outp[(long)b * oStrideB + (long)o * Np + n] = h >= 0.f ? h : 0.2f * h;
}

// ---------------- gemm_colmax ----------------
__global__ void gemm_colmax_kernel(const float* __restrict__ X, int xStrideB, int C, int Np,
                                   const float* __restrict__ W, int ldw, int O,
                                   const float* __restrict__ g, const float* __restrict__ bb,
                                   float* __restrict__ partial) {
  __shared__ float Wt[16][65];
  __shared__ float Xt[16][65];
  int b = blockIdx.z;
  int n0 = blockIdx.x * 64, o0 = blockIdx.y * 64;
  int tid = threadIdx.x;
  int to = tid % 16, tn = tid / 16;
  float acc[4][4] = {};
  for (int c0 = 0; c0 < C; c0 += 16) {
    for (int e = tid; e < 16 * 64; e += 256) {
      int oo = e / 16, kk = e % 16;
      int c = c0 + kk, o = o0 + oo;
      Wt[kk][oo] = (c < C && o < O) ? W[(long)o * ldw + c] : 0.f;
    }
    for (int e = tid; e < 16 * 64; e += 256) {
      int kk = e / 64, nn = e % 64;
      int c = c0 + kk, n = n0 + nn;
      Xt[kk][nn] = (c < C && n < Np) ? X[(long)b * xStrideB + (long)c * Np + n] : 0.f;
    }
    __syncthreads();
    for (int kk = 0; kk < 16; ++kk) {
      float xv[4], wv[4];
      for (int i = 0; i < 4; ++i) xv[i] = Xt[kk][tn + 16 * i];
      for (int j = 0; j < 4; ++j) wv[j] = Wt[kk][to + 16 * j];
      for (int i = 0; i < 4; ++i)
        for (int j = 0; j < 4; ++j) acc[i][j] = fmaf(xv[i], wv[j], acc[i][j]);
    }
    __syncthreads();
  }
  float vm[4];
  for (int j = 0; j < 4; ++j) {
    int o = o0 + to + 16 * j;
    float gs = g[o] * BN_SCALE, bo = bb[o];
    float m = -INFINITY;
    for (int i = 0; i < 4; ++i) {
      float h = acc[i][j] * gs + bo;
      h = h >= 0.f ? h : 0.2f * h;
      m = fmaxf(m, h);
    }
    vm[j] = m;
  }
  for (int j = 0; j < 4; ++j) Xt[tn][to + 16 * j] = vm[j];
  __syncthreads();
  for (int s = 8; s > 0; s >>= 1) {
    if (tn < s)
      for (int j = 0; j < 4; ++j)
        Xt[tn][to + 16 * j] = fmaxf(Xt[tn][to + 16 * j], Xt[tn + s][to + 16 * j]);
    __syncthreads();
  }
  if (tn == 0)
    for (int j = 0; j < 4; ++j) {
      int o = o0 + to + 16 * j;
      partial[((long)b * gridDim.x + blockIdx.x) * O + o] = Xt[0][to + 16 * j];
    }
}

// ---------------- FPS: SINGLE-WAVE per batch — zero barriers, zero cross-wave LDS.
// One 64-lane wave holds all N=2048 points in VGPRs (32/lane, point n = r*64+lane).
// Per iter: 32 independent dist updates; per-lane argmax via 8 parallel sub-scans
// (ascending, strict > keeps smallest r -> smallest n per lane); wave argmax via DPP
// fmax + DPP i32-min over (best==gmax ? n : INT_MAX) -> global min-n among maxima
// (identical to the old 4-wave combine semantics); winner coords via one uniform
// broadcast sp4 read. Float math verbatim -> fidx/node1 bit-identical.
__global__ void __launch_bounds__(64, 1) fps_kernel(const float* __restrict__ xyz, int N, int M,
                                                    int* __restrict__ fpsIdx, float* __restrict__ node1) {
  #pragma clang fp contract(off)
  __shared__ float4 sp4[2048];   // linear: point n at slot n
  __shared__ int fidx[512];
  int b = blockIdx.x, lane = threadIdx.x;
  const float* xb = xyz + (long)b * 3 * N;
  float px[32], py[32], pz[32], dist[32];
  #pragma unroll
  for (int r = 0; r < 32; ++r) {
    int n = r * 64 + lane;
    float X = xb[n], Y = xb[N + n], Z = xb[2 * N + n];
    px[r] = X; py[r] = Y; pz[r] = Z;
    dist[r] = 1e10f;
    sp4[n] = make_float4(X, Y, Z, 0.f);
  }
  int last = 0;
  float lx = xb[0], ly = xb[N], lz = xb[2 * N];   // uniform scalar loads (point 0)
  for (int it = 0; it < M; ++it) {
    if (lane == 0) fidx[it] = last;
    // update all 32 dists (independent, issue-bound)
    #pragma unroll
    for (int r = 0; r < 32; ++r) {
      float dx = px[r] - lx, dy = py[r] - ly, dz = pz[r] - lz;
      float dx2 = dx * dx, dy2 = dy * dy, dz2 = dz * dz;
      float d = (dx2 + dy2) + dz2;
      float t = dist[r];
      dist[r] = (d < t) ? d : t;
    }
    // per-lane argmax: 8 parallel sub-scans of 4 (ascending), then combine ascending.
    // strict > everywhere -> first max in ascending r kept (min n for this lane).
    float bv[8]; int br[8];
    #pragma unroll
    for (int g = 0; g < 8; ++g) {
      float v0 = dist[g * 4]; int r0 = g * 4;
      #pragma unroll
      for (int j = 1; j < 4; ++j) {
        float vj = dist[g * 4 + j];
        bool c = vj > v0;
        v0 = c ? vj : v0;
        r0 = c ? (g * 4 + j) : r0;
      }
      bv[g] = v0; br[g] = r0;
    }
    float best = bv[0]; int ib = br[0];
    #pragma unroll
    for (int g = 1; g < 8; ++g) {
      bool c = bv[g] > best;
      best = c ? bv[g] : best;
      ib = c ? br[g] : ib;
    }
    int mi = (ib << 6) + lane;             // point index n = r*64+lane
    float gmax = wave_fmax(best);
    int cand = (best == gmax) ? mi : 0x7FFFFFFF;
    int big = wave_imin(cand);             // uniform: global min-n among maxima
    last = big;
    float4 lpt = sp4[big];                 // uniform broadcast read (winner coords)
    lx = lpt.x; ly = lpt.y; lz = lpt.z;
  }
  for (int e = lane; e < M; e += 64) fpsIdx[(long)b * M + e] = fidx[e];
  for (int e = lane; e < 3 * M; e += 64) {
    int c = e / M, i = e % M;
    int src = fidx[i];
    float4 ptc = sp4[src];
    node1[(long)b * 3 * M + e] = (c == 0) ? ptc.x : (c == 1) ? ptc.y : ptc.z;
  }
}

// ---------------- xmfill: fused nf1 gather + aggregate gathermax ----------------
__global__ void xmfill_kernel(const float* __restrict__ xt1, int N,
                              const int* __restrict__ fpsI,
                              const int* __restrict__ idxK, int k, int M,
                              float* __restrict__ xm, int B) {
  long t = (long)blockIdx.x * blockDim.x + threadIdx.x;
  long total = (long)B * 128 * M;
  if (t >= total) return;
  int i = (int)(t % M);
  int c = (int)((t / M) % 128);
  int b = (int)(t / ((long)128 * M));
  const float* xb = xt1 + (long)b * 128 * N + (long)c * N;
  float* xmB = xm + (long)b * 256 * M;
  xmB[(long)c * M + i] = xb[fpsI[(long)b * M + i]];
  const int* ip = idxK + ((long)b * M + i) * k;
  float best = -INFINITY;
  for (int kk = 0; kk < k; ++kk) best = fmaxf(best, xb[ip[kk]]);
  xmB[(long)(128 + c) * M + i] = best;
}

// ---------------- head: fused colmax_finish + 3-layer MLP ----------------
__global__ void head_kernel(const float* __restrict__ partA, int NTa,
                            const float* __restrict__ partB, int NTb,
                            const float* __restrict__ Wl1, const float* __restrict__ g6, const float* __restrict__ b6,
                            const float* __restrict__ Wl2, const float* __restrict__ bl2,
                            const float* __restrict__ g7, const float* __restrict__ b7,
                            const float* __restrict__ Wl3, const float* __restrict__ bl3,
                            float* __restrict__ logits) {
  __shared__ float v[2048];
  __shared__ float h1[512];
  __shared__ float h2[256];
  int b = blockIdx.x, tid = threadIdx.x;
  for (int o = tid; o < 1024; o += 256) {
    float m = -INFINITY;
    for (int t = 0; t < NTa; ++t) m = fmaxf(m, partA[((long)b * NTa + t) * 1024 + o]);
    v[o] = m;
    float m2 = -INFINITY;
    for (int t = 0; t < NTb; ++t) m2 = fmaxf(m2, partB[((long)b * NTb + t) * 1024 + o]);
    v[1024 + o] = m2;
  }
  __syncthreads();
  for (int o = tid; o < 512; o += 256) {
    const float* wr = Wl1 + (long)o * 2048;
    float s = 0.f;
    for (int c = 0; c < 2048; c += 4) {
      float4 w4 = *(const float4*)(wr + c);
      s = fmaf(w4.x, v[c], s); s = fmaf(w4.y, v[c + 1], s);
      s = fmaf(w4.z, v[c + 2], s); s = fmaf(w4.w, v[c + 3], s);
    }
    float h = s * (g6[o] * BN_SCALE) + b6[o];
    h1[o] = h >= 0.f ? h : 0.2f * h;
  }
  __syncthreads();
  for (int o = tid; o < 256; o += 256) {
    const float* wr = Wl2 + (long)o * 512;
    float s = 0.f;
    for (int c = 0; c < 512; c += 4) {
      float4 w4 = *(const float4*)(wr + c);
      s = fmaf(w4.x, h1[c], s); s = fmaf(w4.y, h1[c + 1], s);
      s = fmaf(w4.z, h1[c + 2], s); s = fmaf(w4.w, h1[c + 3], s);
    }
    s += bl2[o];
    float h = s * (g7[o] * BN_SCALE) + b7[o];
    h2[o] = h >= 0.f ? h : 0.2f * h;
  }
  __syncthreads();
  if (tid < 40) {
    const float* wr = Wl3 + (long)tid * 256;
    float s = 0.f;
    for (int c = 0; c < 256; ++c) s = fmaf(wr[c], h2[c], s);
    logits[(long)b * 40 + tid] = s + bl3[tid];
  }
}

extern "C" void kernel_launch(void* const* d_in, const int* in_sizes, int n_in,
                              void* d_out, int out_size, void* d_ws, size_t ws_size,
                              hipStream_t stream) {
  const float* x   = (const float*)d_in[0];
  const float* W1  = (const float*)d_in[1];
  const float* g1  = (const float*)d_in[2];
  const float* b1  = (const float*)d_in[3];
  const float* W2  = (const float*)d_in[4];
  const float* g2  = (const float*)d_in[5];
  const float* b2  = (const float*)d_in[6];
  const float* W2m = (const float*)d_in[7];
  const float* g2m = (const float*)d_in[8];
  const float* b2m = (const float*)d_in[9];
  const float* W3  = (const float*)d_in[10];
  const float* g3  = (const float*)d_in[11];
  const float* b3  = (const float*)d_in[12];
  const float* W4  = (const float*)d_in[13];
  const float* g4  = (const float*)d_in[14];
  const float* b4  = (const float*)d_in[15];
  const float* W5  = (const float*)d_in[16];
  const float* g5  = (const float*)d_in[17];
  const float* b5  = (const float*)d_in[18];
  const float* Wl1 = (const float*)d_in[19];
  const float* g6  = (const float*)d_in[20];
  const float* b6  = (const float*)d_in[21];
  const float* Wl2 = (const float*)d_in[22];
  const float* bl2 = (const float*)d_in[23];
  const float* g7  = (const float*)d_in[24];
  const float* b7  = (const float*)d_in[25];
  const float* Wl3 = (const float*)d_in[26];
  const float* bl3 = (const float*)d_in[27];
  float* outF = (float*)d_out;

  const int B = 8, N = 2048, K = 20, M = 512, K2 = 10;

  float* ws    = (float*)d_ws;
  float* xt1   = ws;                               // (B,128,N)
  float* xm    = xt1 + (size_t)B * 128 * N;        // (B,256,M)
  float* xc    = xm  + (size_t)B * 256 * M;        // (B,512,M)
  float* Pt    = xc  + (size_t)B * 512 * M;        // max(B*N*64, B*M*256)
  float* St    = Pt  + (size_t)B * N * 64;
  float* partA = St  + (size_t)B * N * 64;         // (B,32,1024)
  float* partB = partA + (size_t)B * 32 * 1024;    // (B,8,1024)
  int*   idxK  = (int*)(partB + (size_t)B * 8 * 1024);  // (B,N,K)
  int*   fpsI  = idxK + (size_t)B * N * K;         // (B,M)

  float* logits = outF;        // (B,40)
  float* node1  = outF + 320;  // (B,3,M)

  dim3 t256(256);

  // ---- stage 1: knn(xyz) + edge_conv1 -> xt1 ch 0..63
  knn4_kernel<8><<<dim3(N / 4, B), t256, 0, stream>>>(x, 3 * N, x, 3 * N, 3, N, N, K, idxK);
  gemmPS_kernel<<<dim3(N / 64, 1, B), t256, 0, stream>>>(x, 3 * N, 3, N, W1, 6, 64, Pt, St);
  ecfinish_kernel<<<dim3(N / 4, B), dim3(64, 4), 0, stream>>>(Pt, St, idxK, K, 64, N, g1, b1, xt1, (long)128 * N);

  // FPS (xyz only) — single wave per batch
  fps_kernel<<<dim3(B), dim3(64), 0, stream>>>(x, N, M, fpsI, node1);

  // ---- stage 2: knn(x1) + edge_conv2 -> xt1 ch 64..127
  knn4_kernel<8><<<dim3(N / 4, B), t256, 0, stream>>>(xt1, 128 * N, xt1, 128 * N, 64, N, N, K, idxK);
  gemmPS_kernel<<<dim3(N / 64, 1, B), t256, 0, stream>>>(xt1, 128 * N, 64, N, W2, 128, 64, Pt, St);
  ecfinish_kernel<<<dim3(N / 4, B), dim3(64, 4), 0, stream>>>(Pt, St, idxK, K, 64, N, g2, b2,
                                                              xt1 + (size_t)64 * N, (long)128 * N);

  // ---- vf partials
  gemm_colmax_kernel<<<dim3(N / 64, 1024 / 64, B), t256, 0, stream>>>(xt1, 128 * N, 128, N, W2m, 128, 1024,
                                                                      g2m, b2m, partA);

  // ---- aggregate knn (node1 vs xyz), then fused xm fill
  knn4_kernel<8><<<dim3(M / 4, B), t256, 0, stream>>>(node1, 3 * M, x, 3 * N, 3, M, N, K, idxK);
  xmfill_kernel<<<dim3((B * 128 * M + 255) / 256), t256, 0, stream>>>(xt1, N, fpsI, idxK, K, M, xm, B);

  // ---- stage 3: knn(xm) + edge_conv3 -> xc ch 0..255
  knn4_kernel<2><<<dim3(M / 4, B), t256, 0, stream>>>(xm, 256 * M, xm, 256 * M, 256, M, M, K2, idxK);
  gemmPS_kernel<<<dim3(M / 64, 256 / 64, B), t256, 0, stream>>>(xm, 256 * M, 256, M, W3, 512, 256, Pt, St);
  ecfinish_kernel<<<dim3(M, B), dim3(256, 1), 0, stream>>>(Pt, St, idxK, K2, 256, M, g3, b3, xc, (long)512 * M);

  // ---- stage 4: knn(x3) + edge_conv4 -> xc ch 256..511
  knn4_kernel<2><<<dim3(M / 4, B), t256, 0, stream>>>(xc, 512 * M, xc, 512 * M, 256, M, M, K2, idxK);
  gemmPS_kernel<<<dim3(M / 64, 256 / 64, B), t256, 0, stream>>>(xc, 512 * M, 256, M, W4, 512, 256, Pt, St);
  ecfinish_kernel<<<dim3(M, B), dim3(256, 1), 0, stream>>>(Pt, St, idxK, K2, 256, M, g4, b4,
                                                           xc + (size_t)256 * M, (long)512 * M);

  // ---- vs partials
  gemm_colmax_kernel<<<dim3(M / 64, 1024 / 64, B), t256, 0, stream>>>(xc, 512 * M, 512, M, W5, 512, 1024,
                                                                      g5, b5, partB);

  // ---- head (fused colmax_finish + MLP)
  head_kernel<<<dim3(B), t256, 0, stream>>>(partA, N / 64, partB, M / 64,
                                            Wl1, g6, b6, Wl2, bl2, g7, b7, Wl3, bl3, logits);
}

// Round 6
// 1454.445 us; speedup vs baseline: 1.1337x; 1.1337x over previous
//
#include <hip/hip_runtime.h>

#define BN_SCALE 0.9999950000374997f  // 1/sqrt(1+1e-5)

// ---- DPP full-wave reductions (validated in fps/knn since R2/R4) ----
template <int CTRL>
__device__ __forceinline__ float dpp_fmax_step(float v) {
  int xi = __builtin_bit_cast(int, v);
  int ti = __builtin_amdgcn_update_dpp(xi, xi, CTRL, 0xf, 0xf, false);  // invalid lanes -> old(=v)
  return fmaxf(v, __builtin_bit_cast(float, ti));
}
template <int CTRL>
__device__ __forceinline__ int dpp_imin_step(int v) {
  int t = __builtin_amdgcn_update_dpp(v, v, CTRL, 0xf, 0xf, false);    // invalid lanes -> old(=v)
  return (t < v) ? t : v;
}
__device__ __forceinline__ float wave_fmax(float v) {
  v = dpp_fmax_step<0x111>(v);  // row_shr:1
  v = dpp_fmax_step<0x112>(v);  // row_shr:2
  v = dpp_fmax_step<0x114>(v);  // row_shr:4
  v = dpp_fmax_step<0x118>(v);  // row_shr:8
  v = dpp_fmax_step<0x142>(v);  // row_bcast:15
  v = dpp_fmax_step<0x143>(v);  // row_bcast:31
  return __builtin_bit_cast(float, __builtin_amdgcn_readlane(__builtin_bit_cast(int, v), 63));
}
__device__ __forceinline__ int wave_imin(int v) {
  v = dpp_imin_step<0x111>(v);
  v = dpp_imin_step<0x112>(v);
  v = dpp_imin_step<0x114>(v);
  v = dpp_imin_step<0x118>(v);
  v = dpp_imin_step<0x142>(v);
  v = dpp_imin_step<0x143>(v);
  return __builtin_amdgcn_readlane(v, 63);
}

// ---------------- knn4 body (R4 version) as a device function ----------------
template <int R>
__device__ __forceinline__ void knn4_body(const float* __restrict__ Q, int qStrideB,
                                          const float* __restrict__ Xc, int cStrideB,
                                          int C, int M, int N, int k, int* __restrict__ idxOut,
                                          int b, int q0, char* smem) {
  constexpr int NR = 4 * R;                          // values per lane in selection
  float (*negd)[R * 256] = (float (*)[R * 256])smem;
  int tid = threadIdx.x;
  const float* qb = Q + (long)b * qStrideB + q0;     // + c*M walks channels (uniform)
  const float* cb = Xc + (long)b * cStrideB;         // uniform
  float d0[R], d1[R], d2[R], d3[R], sq[R];
  #pragma unroll
  for (int i = 0; i < R; ++i) { d0[i] = d1[i] = d2[i] = d3[i] = sq[i] = 0.f; }
  for (int c = 0; c < C; ++c) {
    float4 q4 = *(const float4*)(qb + (long)c * M);  // uniform -> scalar load
    const float* pc = cb + (long)c * N;              // uniform base
    #pragma unroll
    for (int i = 0; i < R; ++i) {
      float xv = pc[tid + 256 * i];
      sq[i] = fmaf(xv, xv, sq[i]);
      d0[i] = fmaf(q4.x, xv, d0[i]);
      d1[i] = fmaf(q4.y, xv, d1[i]);
      d2[i] = fmaf(q4.z, xv, d2[i]);
      d3[i] = fmaf(q4.w, xv, d3[i]);
    }
  }
  #pragma unroll
  for (int i = 0; i < R; ++i) {
    int m = tid + 256 * i;
    negd[0][m] = 2.f * d0[i] - sq[i];
    negd[1][m] = 2.f * d1[i] - sq[i];
    negd[2][m] = 2.f * d2[i] - sq[i];
    negd[3][m] = 2.f * d3[i] - sq[i];
  }
  __syncthreads();
  int lane = tid & 63, w = tid >> 6;
  const float* row = negd[w];
  int* outp = idxOut + ((long)b * M + (q0 + w)) * k;
  float v[NR];
  #pragma unroll
  for (int i = 0; i < NR; ++i) v[i] = row[lane + 64 * i];   // conflict-free, once
  for (int kk = 0; kk < k; ++kk) {
    float best = -INFINITY; int ib = 0;
    #pragma unroll
    for (int i = 0; i < NR; ++i) {
      bool c = v[i] > best;                 // strict > : first (smallest m) kept on ties
      best = c ? v[i] : best;
      ib = c ? i : ib;
    }
    int bi = (best > -INFINITY) ? (lane + (ib << 6)) : N;   // all-removed lane -> N (orig sem)
    float gmax = wave_fmax(best);
    int cand = (best == gmax) ? bi : 0x7FFFFFFF;
    int big = wave_imin(cand);              // smallest index among global maxima (uniform)
    if (lane == 0) outp[kk] = big;
    int ri = big >> 6;                      // uniform
    bool mine = (lane == (big & 63));
    #pragma unroll
    for (int i = 0; i < NR; ++i)
      if (i == ri) v[i] = mine ? -INFINITY : v[i];          // i==ri uniform -> 1 cndmask
  }
}

template <int R>
__global__ void knn4_kernel(const float* __restrict__ Q, int qStrideB,
                            const float* __restrict__ Xc, int cStrideB,
                            int C, int M, int N, int k, int* __restrict__ idxOut) {
  __shared__ __align__(16) char smem[R * 256 * 4 * 4];
  knn4_body<R>(Q, qStrideB, Xc, cStrideB, C, M, N, k, idxOut,
               blockIdx.y, blockIdx.x * 4, smem);
}

// ---------------- FPS body: 4-wave R2 structure + DPP-imin winner selection.
// Selection semantics identical to R2's ballot/ffs path (lanes ascend with index
// blocks base=tid*8; within-lane first-max kept -> wave_imin over maxima gives the
// same min-index argmax) -> fidx/node1 bit-identical.
__device__ __forceinline__ void fps_body(const float* __restrict__ xyz, int N, int M,
                                         int* __restrict__ fpsIdx, float* __restrict__ node1,
                                         int b, char* smem) {
  #pragma clang fp contract(off)
  float4* sp4 = (float4*)smem;                 // 2048 pts: slot (n&7)*256 + (n>>3); 32768 B
  int*    fidx = (int*)(smem + 32768);         // 512 ints; 2048 B
  float4* wvc  = (float4*)(smem + 32768 + 2048);      // [2][4] {gmax,x,y,z}; 128 B
  int*    wis  = (int*)(smem + 32768 + 2048 + 128);   // [2][4]; 32 B
  int tid = threadIdx.x;
  int lane = tid & 63, w = tid >> 6;
  const float* xb = xyz + (long)b * 3 * N;
  for (int n = tid; n < N; n += 256) {
    sp4[((n & 7) << 8) | (n >> 3)] = make_float4(xb[n], xb[N + n], xb[2 * N + n], 0.f);
  }
  __syncthreads();
  float4 pt[8];
  #pragma unroll
  for (int i = 0; i < 8; ++i) pt[i] = sp4[(i << 8) | tid];   // point tid*8+i, in VGPRs
  float dist[8];
  #pragma unroll
  for (int i = 0; i < 8; ++i) dist[i] = 1e10f;
  int base = tid * 8;
  int last = 0;
  float4 l0 = sp4[0];            // point 0 (slot 0), broadcast read once
  float lx = l0.x, ly = l0.y, lz = l0.z;
  for (int it = 0; it < M; ++it) {
    int p = it & 1;
    if (tid == 0) fidx[it] = last;
    float best = -INFINITY; int bi = N;
    #pragma unroll
    for (int i = 0; i < 8; ++i) {
      float dx = pt[i].x - lx, dy = pt[i].y - ly, dz = pt[i].z - lz;
      float dx2 = dx * dx, dy2 = dy * dy, dz2 = dz * dz;
      float d = (dx2 + dy2) + dz2;
      float dn = dist[i];
      if (d < dn) dn = d;
      dist[i] = dn;
      if (dn > best) { best = dn; bi = base + i; }  // ascending -> first max in lane kept
    }
    // per-thread coords of its own best point (register select; off critical path)
    float cx = pt[0].x, cy = pt[0].y, cz = pt[0].z;
    #pragma unroll
    for (int i = 1; i < 8; ++i) {
      bool c = (bi == base + i);
      cx = c ? pt[i].x : cx; cy = c ? pt[i].y : cy; cz = c ? pt[i].z : cz;
    }
    // wave argmax: DPP fmax, then DPP imin over candidate indices (min-index among maxima)
    float gmax = wave_fmax(best);
    int cand = (best == gmax) ? bi : 0x7FFFFFFF;
    int wbi = wave_imin(cand);                       // uniform
    if (bi == wbi) { wvc[p * 4 + w] = make_float4(gmax, cx, cy, cz); wis[p * 4 + w] = wbi; }
    __syncthreads();
    // all threads redundantly combine the 4 wave results (waves ascend in index)
    float4 c0 = wvc[p * 4 + 0], c1 = wvc[p * 4 + 1], c2 = wvc[p * 4 + 2], c3 = wvc[p * 4 + 3];
    int i0 = wis[p * 4 + 0], i1 = wis[p * 4 + 1], i2 = wis[p * 4 + 2], i3 = wis[p * 4 + 3];
    float bv = c0.x; int bbi = i0; lx = c0.y; ly = c0.z; lz = c0.w;
    { bool c = (c1.x > bv) || (c1.x == bv && i1 < bbi);
      bv = c ? c1.x : bv; bbi = c ? i1 : bbi; lx = c ? c1.y : lx; ly = c ? c1.z : ly; lz = c ? c1.w : lz; }
    { bool c = (c2.x > bv) || (c2.x == bv && i2 < bbi);
      bv = c ? c2.x : bv; bbi = c ? i2 : bbi; lx = c ? c2.y : lx; ly = c ? c2.z : ly; lz = c ? c2.w : lz; }
    { bool c = (c3.x > bv) || (c3.x == bv && i3 < bbi);
      bv = c ? c3.x : bv; bbi = c ? i3 : bbi; lx = c ? c3.y : lx; ly = c ? c3.z : ly; lz = c ? c3.w : lz; }
    last = bbi;
    // parity: slot p rewritten only in iter it+2, after barrier it+1 -> safe with 1 barrier
  }
  for (int e = tid; e < M; e += 256) fpsIdx[(long)b * M + e] = fidx[e];
  for (int e = tid; e < 3 * M; e += 256) {
    int c = e / M, i = e % M;
    int src = fidx[i];
    float4 ptc = sp4[((src & 7) << 8) | (src >> 3)];
    node1[(long)b * 3 * M + e] = (c == 0) ? ptc.x : (c == 1) ? ptc.y : ptc.z;
  }
}

// ---------------- fused stage-2 knn + FPS: fps and stage-2 knn are independent
// (fps reads x; knn reads xt1; fps outputs first consumed after the stage-2 chain).
// blockIdx.x==0 -> fps (dispatched first, fills 8 CUs); else knn query block.
__global__ void knn4fps_kernel(const float* __restrict__ Q, int qStrideB,
                               const float* __restrict__ Xc, int cStrideB,
                               int C, int M, int N, int k, int* __restrict__ idxOut,
                               const float* __restrict__ xyz, int Mf,
                               int* __restrict__ fpsIdx, float* __restrict__ node1) {
  __shared__ __align__(16) char smem[32768 + 2048 + 128 + 32];   // union: knn 32KB | fps 34.9KB
  if (blockIdx.x == 0) {
    fps_body(xyz, N, Mf, fpsIdx, node1, blockIdx.y, smem);
  } else {
    knn4_body<8>(Q, qStrideB, Xc, cStrideB, C, M, N, k, idxOut,
                 blockIdx.y, (blockIdx.x - 1) * 4, smem);
  }
}

// ---------------- gemmPS: one pass computes BOTH halves of the edge-conv weight ----------------
__global__ void gemmPS_kernel(const float* __restrict__ X, int xStrideB, int C, int Np,
                              const float* __restrict__ W, int ldw, int O,
                              float* __restrict__ PtT, float* __restrict__ StT) {
  __shared__ float Wp[16][65];
  __shared__ float Ws[16][65];
  __shared__ float Xt[16][65];
  int b = blockIdx.z;
  int n0 = blockIdx.x * 64, o0 = blockIdx.y * 64;
  int tid = threadIdx.x;
  int to = tid % 16, tn = tid / 16;
  float accP[4][4] = {}, accS[4][4] = {};
  for (int c0 = 0; c0 < C; c0 += 16) {
    for (int e = tid; e < 16 * 64; e += 256) {
      int oo = e / 16, kk = e % 16;
      int c = c0 + kk, o = o0 + oo;
      bool ok = (c < C && o < O);
      Wp[kk][oo] = ok ? W[(long)o * ldw + c] : 0.f;
      Ws[kk][oo] = ok ? W[(long)o * ldw + C + c] : 0.f;
    }
    for (int e = tid; e < 16 * 64; e += 256) {
      int kk = e / 64, nn = e % 64;
      int c = c0 + kk, n = n0 + nn;
      Xt[kk][nn] = (c < C && n < Np) ? X[(long)b * xStrideB + (long)c * Np + n] : 0.f;
    }
    __syncthreads();
    for (int kk = 0; kk < 16; ++kk) {
      float xv[4], wp[4], ws[4];
      for (int i = 0; i < 4; ++i) xv[i] = Xt[kk][tn + 16 * i];
      for (int j = 0; j < 4; ++j) { wp[j] = Wp[kk][to + 16 * j]; ws[j] = Ws[kk][to + 16 * j]; }
      for (int i = 0; i < 4; ++i)
        for (int j = 0; j < 4; ++j) {
          accP[i][j] = fmaf(xv[i], wp[j], accP[i][j]);
          accS[i][j] = fmaf(xv[i], ws[j], accS[i][j]);
        }
    }
    __syncthreads();
  }
  for (int i = 0; i < 4; ++i) {
    int n = n0 + tn + 16 * i;
    if (n >= Np) continue;
    for (int j = 0; j < 4; ++j) {
      int o = o0 + to + 16 * j;
      if (o < O) {
        long off = ((long)b * Np + n) * O + o;
        PtT[off] = accP[i][j];
        StT[off] = accS[i][j];
      }
    }
  }
}

// ---------------- ecfinish ----------------
__global__ void ecfinish_kernel(const float* __restrict__ Pt, const float* __restrict__ St,
                                const int* __restrict__ idx, int k, int O, int Np,
                                const float* __restrict__ g, const float* __restrict__ bb,
                                float* __restrict__ outp, long oStrideB) {
  int b = blockIdx.y;
  int n = blockIdx.x * blockDim.y + threadIdx.y;
  int o = threadIdx.x;
  const float* PtB = Pt + (long)b * Np * O;
  const float* StB = St + (long)b * Np * O;
  const int* ip = idx + ((long)b * Np + n) * k;
  float mx = -INFINITY, mn = INFINITY;
  for (int kk = 0; kk < k; ++kk) {
    float v = PtB[(long)ip[kk] * O + o];
    mx = fmaxf(mx, v); mn = fminf(mn, v);
  }
  float ctrP = PtB[(long)n * O + o];
  float ctrS = StB[(long)n * O + o];
  float gs = g[o] * BN_SCALE;
  float m = (gs >= 0.f) ? mx : mn;
  float h = (ctrS - ctrP + m) * gs + bb[o];
  outp[(long)b * oStrideB + (long)o * Np + n] = h >= 0.f ? h : 0.2f * h;
}

// ---------------- gemm_colmax ----------------
__global__ void gemm_colmax_kernel(const float* __restrict__ X, int xStrideB, int C, int Np,
                                   const float* __restrict__ W, int ldw, int O,
                                   const float* __restrict__ g, const float* __restrict__ bb,
                                   float* __restrict__ partial) {
  __shared__ float Wt[16][65];
  __shared__ float Xt[16][65];
  int b = blockIdx.z;
  int n0 = blockIdx.x * 64, o0 = blockIdx.y * 64;
  int tid = threadIdx.x;
  int to = tid % 16, tn = tid / 16;
  float acc[4][4] = {};
  for (int c0 = 0; c0 < C; c0 += 16) {
    for (int e = tid; e < 16 * 64; e += 256) {
      int oo = e / 16, kk = e % 16;
      int c = c0 + kk, o = o0 + oo;
      Wt[kk][oo] = (c < C && o < O) ? W[(long)o * ldw + c] : 0.f;
    }
    for (int e = tid; e < 16 * 64; e += 256) {
      int kk = e / 64, nn = e % 64;
      int c = c0 + kk, n = n0 + nn;
      Xt[kk][nn] = (c < C && n < Np) ? X[(long)b * xStrideB + (long)c * Np + n] : 0.f;
    }
    __syncthreads();
    for (int kk = 0; kk < 16; ++kk) {
      float xv[4], wv[4];
      for (int i = 0; i < 4; ++i) xv[i] = Xt[kk][tn + 16 * i];
      for (int j = 0; j < 4; ++j) wv[j] = Wt[kk][to + 16 * j];
      for (int i = 0; i < 4; ++i)
        for (int j = 0; j < 4; ++j) acc[i][j] = fmaf(xv[i], wv[j], acc[i][j]);
    }
    __syncthreads();
  }
  float vm[4];
  for (int j = 0; j < 4; ++j) {
    int o = o0 + to + 16 * j;
    float gs = g[o] * BN_SCALE, bo = bb[o];
    float m = -INFINITY;
    for (int i = 0; i < 4; ++i) {
      float h = acc[i][j] * gs + bo;
      h = h >= 0.f ? h : 0.2f * h;
      m = fmaxf(m, h);
    }
    vm[j] = m;
  }
  for (int j = 0; j < 4; ++j) Xt[tn][to + 16 * j] = vm[j];
  __syncthreads();
  for (int s = 8; s > 0; s >>= 1) {
    if (tn < s)
      for (int j = 0; j < 4; ++j)
        Xt[tn][to + 16 * j] = fmaxf(Xt[tn][to + 16 * j], Xt[tn + s][to + 16 * j]);
    __syncthreads();
  }
  if (tn == 0)
    for (int j = 0; j < 4; ++j) {
      int o = o0 + to + 16 * j;
      partial[((long)b * gridDim.x + blockIdx.x) * O + o] = Xt[0][to + 16 * j];
    }
}

// ---------------- xmfill: fused nf1 gather + aggregate gathermax ----------------
__global__ void xmfill_kernel(const float* __restrict__ xt1, int N,
                              const int* __restrict__ fpsI,
                              const int* __restrict__ idxK, int k, int M,
                              float* __restrict__ xm, int B) {
  long t = (long)blockIdx.x * blockDim.x + threadIdx.x;
  long total = (long)B * 128 * M;
  if (t >= total) return;
  int i = (int)(t % M);
  int c = (int)((t / M) % 128);
  int b = (int)(t / ((long)128 * M));
  const float* xb = xt1 + (long)b * 128 * N + (long)c * N;
  float* xmB = xm + (long)b * 256 * M;
  xmB[(long)c * M + i] = xb[fpsI[(long)b * M + i]];
  const int* ip = idxK + ((long)b * M + i) * k;
  float best = -INFINITY;
  for (int kk = 0; kk < k; ++kk) best = fmaxf(best, xb[ip[kk]]);
  xmB[(long)(128 + c) * M + i] = best;
}

// ---------------- head: fused colmax_finish + 3-layer MLP ----------------
__global__ void head_kernel(const float* __restrict__ partA, int NTa,
                            const float* __restrict__ partB, int NTb,
                            const float* __restrict__ Wl1, const float* __restrict__ g6, const float* __restrict__ b6,
                            const float* __restrict__ Wl2, const float* __restrict__ bl2,
                            const float* __restrict__ g7, const float* __restrict__ b7,
                            const float* __restrict__ Wl3, const float* __restrict__ bl3,
                            float* __restrict__ logits) {
  __shared__ float v[2048];
  __shared__ float h1[512];
  __shared__ float h2[256];
  int b = blockIdx.x, tid = threadIdx.x;
  for (int o = tid; o < 1024; o += 256) {
    float m = -INFINITY;
    for (int t = 0; t < NTa; ++t) m = fmaxf(m, partA[((long)b * NTa + t) * 1024 + o]);
    v[o] = m;
    float m2 = -INFINITY;
    for (int t = 0; t < NTb; ++t) m2 = fmaxf(m2, partB[((long)b * NTb + t) * 1024 + o]);
    v[1024 + o] = m2;
  }
  __syncthreads();
  for (int o = tid; o < 512; o += 256) {
    const float* wr = Wl1 + (long)o * 2048;
    float s = 0.f;
    for (int c = 0; c < 2048; c += 4) {
      float4 w4 = *(const float4*)(wr + c);
      s = fmaf(w4.x, v[c], s); s = fmaf(w4.y, v[c + 1], s);
      s = fmaf(w4.z, v[c + 2], s); s = fmaf(w4.w, v[c + 3], s);
    }
    float h = s * (g6[o] * BN_SCALE) + b6[o];
    h1[o] = h >= 0.f ? h : 0.2f * h;
  }
  __syncthreads();
  for (int o = tid; o < 256; o += 256) {
    const float* wr = Wl2 + (long)o * 512;
    float s = 0.f;
    for (int c = 0; c < 512; c += 4) {
      float4 w4 = *(const float4*)(wr + c);
      s = fmaf(w4.x, h1[c], s); s = fmaf(w4.y, h1[c + 1], s);
      s = fmaf(w4.z, h1[c + 2], s); s = fmaf(w4.w, h1[c + 3], s);
    }
    s += bl2[o];
    float h = s * (g7[o] * BN_SCALE) + b7[o];
    h2[o] = h >= 0.f ? h : 0.2f * h;
  }
  __syncthreads();
  if (tid < 40) {
    const float* wr = Wl3 + (long)tid * 256;
    float s = 0.f;
    for (int c = 0; c < 256; ++c) s = fmaf(wr[c], h2[c], s);
    logits[(long)b * 40 + tid] = s + bl3[tid];
  }
}

extern "C" void kernel_launch(void* const* d_in, const int* in_sizes, int n_in,
                              void* d_out, int out_size, void* d_ws, size_t ws_size,
                              hipStream_t stream) {
  const float* x   = (const float*)d_in[0];
  const float* W1  = (const float*)d_in[1];
  const float* g1  = (const float*)d_in[2];
  const float* b1  = (const float*)d_in[3];
  const float* W2  = (const float*)d_in[4];
  const float* g2  = (const float*)d_in[5];
  const float* b2  = (const float*)d_in[6];
  const float* W2m = (const float*)d_in[7];
  const float* g2m = (const float*)d_in[8];
  const float* b2m = (const float*)d_in[9];
  const float* W3  = (const float*)d_in[10];
  const float* g3  = (const float*)d_in[11];
  const float* b3  = (const float*)d_in[12];
  const float* W4  = (const float*)d_in[13];
  const float* g4  = (const float*)d_in[14];
  const float* b4  = (const float*)d_in[15];
  const float* W5  = (const float*)d_in[16];
  const float* g5  = (const float*)d_in[17];
  const float* b5  = (const float*)d_in[18];
  const float* Wl1 = (const float*)d_in[19];
  const float* g6  = (const float*)d_in[20];
  const float* b6  = (const float*)d_in[21];
  const float* Wl2 = (const float*)d_in[22];
  const float* bl2 = (const float*)d_in[23];
  const float* g7  = (const float*)d_in[24];
  const float* b7  = (const float*)d_in[25];
  const float* Wl3 = (const float*)d_in[26];
  const float* bl3 = (const float*)d_in[27];
  float* outF = (float*)d_out;

  const int B = 8, N = 2048, K = 20, M = 512, K2 = 10;

  float* ws    = (float*)d_ws;
  float* xt1   = ws;                               // (B,128,N)
  float* xm    = xt1 + (size_t)B * 128 * N;        // (B,256,M)
  float* xc    = xm  + (size_t)B * 256 * M;        // (B,512,M)
  float* Pt    = xc  + (size_t)B * 512 * M;        // max(B*N*64, B*M*256)
  float* St    = Pt  + (size_t)B * N * 64;
  float* partA = St  + (size_t)B * N * 64;         // (B,32,1024)
  float* partB = partA + (size_t)B * 32 * 1024;    // (B,8,1024)
  int*   idxK  = (int*)(partB + (size_t)B * 8 * 1024);  // (B,N,K)
  int*   fpsI  = idxK + (size_t)B * N * K;         // (B,M)

  float* logits = outF;        // (B,40)
  float* node1  = outF + 320;  // (B,3,M)

  dim3 t256(256);

  // ---- stage 1: knn(xyz) + edge_conv1 -> xt1 ch 0..63
  knn4_kernel<8><<<dim3(N / 4, B), t256, 0, stream>>>(x, 3 * N, x, 3 * N, 3, N, N, K, idxK);
  gemmPS_kernel<<<dim3(N / 64, 1, B), t256, 0, stream>>>(x, 3 * N, 3, N, W1, 6, 64, Pt, St);
  ecfinish_kernel<<<dim3(N / 4, B), dim3(64, 4), 0, stream>>>(Pt, St, idxK, K, 64, N, g1, b1, xt1, (long)128 * N);

  // ---- stage 2: knn(x1) FUSED with FPS (independent work, concurrent blocks)
  knn4fps_kernel<<<dim3(1 + N / 4, B), t256, 0, stream>>>(xt1, 128 * N, xt1, 128 * N, 64, N, N, K, idxK,
                                                          x, M, fpsI, node1);
  gemmPS_kernel<<<dim3(N / 64, 1, B), t256, 0, stream>>>(xt1, 128 * N, 64, N, W2, 128, 64, Pt, St);
  ecfinish_kernel<<<dim3(N / 4, B), dim3(64, 4), 0, stream>>>(Pt, St, idxK, K, 64, N, g2, b2,
                                                              xt1 + (size_t)64 * N, (long)128 * N);

  // ---- vf partials
  gemm_colmax_kernel<<<dim3(N / 64, 1024 / 64, B), t256, 0, stream>>>(xt1, 128 * N, 128, N, W2m, 128, 1024,
                                                                      g2m, b2m, partA);

  // ---- aggregate knn (node1 vs xyz), then fused xm fill
  knn4_kernel<8><<<dim3(M / 4, B), t256, 0, stream>>>(node1, 3 * M, x, 3 * N, 3, M, N, K, idxK);
  xmfill_kernel<<<dim3((B * 128 * M + 255) / 256), t256, 0, stream>>>(xt1, N, fpsI, idxK, K, M, xm, B);

  // ---- stage 3: knn(xm) + edge_conv3 -> xc ch 0..255
  knn4_kernel<2><<<dim3(M / 4, B), t256, 0, stream>>>(xm, 256 * M, xm, 256 * M, 256, M, M, K2, idxK);
  gemmPS_kernel<<<dim3(M / 64, 256 / 64, B), t256, 0, stream>>>(xm, 256 * M, 256, M, W3, 512, 256, Pt, St);
  ecfinish_kernel<<<dim3(M, B), dim3(256, 1), 0, stream>>>(Pt, St, idxK, K2, 256, M, g3, b3, xc, (long)512 * M);

  // ---- stage 4: knn(x3) + edge_conv4 -> xc ch 256..511
  knn4_kernel<2><<<dim3(M / 4, B), t256, 0, stream>>>(xc, 512 * M, xc, 512 * M, 256, M, M, K2, idxK);
  gemmPS_kernel<<<dim3(M / 64, 256 / 64, B), t256, 0, stream>>>(xc, 512 * M, 256, M, W4, 512, 256, Pt, St);
  ecfinish_kernel<<<dim3(M, B), dim3(256, 1), 0, stream>>>(Pt, St, idxK, K2, 256, M, g4, b4,
                                                           xc + (size_t)256 * M, (long)512 * M);

  // ---- vs partials
  gemm_colmax_kernel<<<dim3(M / 64, 1024 / 64, B), t256, 0, stream>>>(xc, 512 * M, 512, M, W5, 512, 1024,
                                                                      g5, b5, partB);

  // ---- head (fused colmax_finish + MLP)
  head_kernel<<<dim3(B), t256, 0, stream>>>(partA, N / 64, partB, M / 64,
                                            Wl1, g6, b6, Wl2, bl2, g7, b7, Wl3, bl3, logits);
}

// Round 7
// 1451.183 us; speedup vs baseline: 1.1363x; 1.0022x over previous
//
#include <hip/hip_runtime.h>

#define BN_SCALE 0.9999950000374997f  // 1/sqrt(1+1e-5)

// ---- DPP full-wave reductions (validated in fps/knn since R2/R4) ----
template <int CTRL>
__device__ __forceinline__ float dpp_fmax_step(float v) {
  int xi = __builtin_bit_cast(int, v);
  int ti = __builtin_amdgcn_update_dpp(xi, xi, CTRL, 0xf, 0xf, false);  // invalid lanes -> old(=v)
  return fmaxf(v, __builtin_bit_cast(float, ti));
}
template <int CTRL>
__device__ __forceinline__ int dpp_imin_step(int v) {
  int t = __builtin_amdgcn_update_dpp(v, v, CTRL, 0xf, 0xf, false);    // invalid lanes -> old(=v)
  return (t < v) ? t : v;
}
__device__ __forceinline__ float wave_fmax(float v) {
  v = dpp_fmax_step<0x111>(v);  // row_shr:1
  v = dpp_fmax_step<0x112>(v);  // row_shr:2
  v = dpp_fmax_step<0x114>(v);  // row_shr:4
  v = dpp_fmax_step<0x118>(v);  // row_shr:8
  v = dpp_fmax_step<0x142>(v);  // row_bcast:15
  v = dpp_fmax_step<0x143>(v);  // row_bcast:31
  return __builtin_bit_cast(float, __builtin_amdgcn_readlane(__builtin_bit_cast(int, v), 63));
}
__device__ __forceinline__ int wave_imin(int v) {
  v = dpp_imin_step<0x111>(v);
  v = dpp_imin_step<0x112>(v);
  v = dpp_imin_step<0x114>(v);
  v = dpp_imin_step<0x118>(v);
  v = dpp_imin_step<0x142>(v);
  v = dpp_imin_step<0x143>(v);
  return __builtin_amdgcn_readlane(v, 63);
}

// ---------------- knn4 body (R4 version) as a device function ----------------
template <int R>
__device__ __forceinline__ void knn4_body(const float* __restrict__ Q, int qStrideB,
                                          const float* __restrict__ Xc, int cStrideB,
                                          int C, int M, int N, int k, int* __restrict__ idxOut,
                                          int b, int q0, char* smem) {
  constexpr int NR = 4 * R;                          // values per lane in selection
  float (*negd)[R * 256] = (float (*)[R * 256])smem;
  int tid = threadIdx.x;
  const float* qb = Q + (long)b * qStrideB + q0;     // + c*M walks channels (uniform)
  const float* cb = Xc + (long)b * cStrideB;         // uniform
  float d0[R], d1[R], d2[R], d3[R], sq[R];
  #pragma unroll
  for (int i = 0; i < R; ++i) { d0[i] = d1[i] = d2[i] = d3[i] = sq[i] = 0.f; }
  for (int c = 0; c < C; ++c) {
    float4 q4 = *(const float4*)(qb + (long)c * M);  // uniform -> scalar load
    const float* pc = cb + (long)c * N;              // uniform base
    #pragma unroll
    for (int i = 0; i < R; ++i) {
      float xv = pc[tid + 256 * i];
      sq[i] = fmaf(xv, xv, sq[i]);
      d0[i] = fmaf(q4.x, xv, d0[i]);
      d1[i] = fmaf(q4.y, xv, d1[i]);
      d2[i] = fmaf(q4.z, xv, d2[i]);
      d3[i] = fmaf(q4.w, xv, d3[i]);
    }
  }
  #pragma unroll
  for (int i = 0; i < R; ++i) {
    int m = tid + 256 * i;
    negd[0][m] = 2.f * d0[i] - sq[i];
    negd[1][m] = 2.f * d1[i] - sq[i];
    negd[2][m] = 2.f * d2[i] - sq[i];
    negd[3][m] = 2.f * d3[i] - sq[i];
  }
  __syncthreads();
  int lane = tid & 63, w = tid >> 6;
  const float* row = negd[w];
  int* outp = idxOut + ((long)b * M + (q0 + w)) * k;
  float v[NR];
  #pragma unroll
  for (int i = 0; i < NR; ++i) v[i] = row[lane + 64 * i];   // conflict-free, once
  for (int kk = 0; kk < k; ++kk) {
    float best = -INFINITY; int ib = 0;
    #pragma unroll
    for (int i = 0; i < NR; ++i) {
      bool c = v[i] > best;                 // strict > : first (smallest m) kept on ties
      best = c ? v[i] : best;
      ib = c ? i : ib;
    }
    int bi = (best > -INFINITY) ? (lane + (ib << 6)) : N;   // all-removed lane -> N (orig sem)
    float gmax = wave_fmax(best);
    int cand = (best == gmax) ? bi : 0x7FFFFFFF;
    int big = wave_imin(cand);              // smallest index among global maxima (uniform)
    if (lane == 0) outp[kk] = big;
    int ri = big >> 6;                      // uniform
    bool mine = (lane == (big & 63));
    #pragma unroll
    for (int i = 0; i < NR; ++i)
      if (i == ri) v[i] = mine ? -INFINITY : v[i];          // i==ri uniform -> 1 cndmask
  }
}

template <int R>
__global__ void knn4_kernel(const float* __restrict__ Q, int qStrideB,
                            const float* __restrict__ Xc, int cStrideB,
                            int C, int M, int N, int k, int* __restrict__ idxOut) {
  __shared__ __align__(16) char smem[R * 256 * 4 * 4];
  knn4_body<R>(Q, qStrideB, Xc, cStrideB, C, M, N, k, idxOut,
               blockIdx.y, blockIdx.x * 4, smem);
}

// ---------------- FPS body: 4-wave R2 structure + DPP-imin winner selection.
__device__ __forceinline__ void fps_body(const float* __restrict__ xyz, int N, int M,
                                         int* __restrict__ fpsIdx, float* __restrict__ node1,
                                         int b, char* smem) {
  #pragma clang fp contract(off)
  float4* sp4 = (float4*)smem;                 // 2048 pts: slot (n&7)*256 + (n>>3); 32768 B
  int*    fidx = (int*)(smem + 32768);         // 512 ints; 2048 B
  float4* wvc  = (float4*)(smem + 32768 + 2048);      // [2][4] {gmax,x,y,z}; 128 B
  int*    wis  = (int*)(smem + 32768 + 2048 + 128);   // [2][4]; 32 B
  int tid = threadIdx.x;
  int lane = tid & 63, w = tid >> 6;
  const float* xb = xyz + (long)b * 3 * N;
  for (int n = tid; n < N; n += 256) {
    sp4[((n & 7) << 8) | (n >> 3)] = make_float4(xb[n], xb[N + n], xb[2 * N + n], 0.f);
  }
  __syncthreads();
  float4 pt[8];
  #pragma unroll
  for (int i = 0; i < 8; ++i) pt[i] = sp4[(i << 8) | tid];   // point tid*8+i, in VGPRs
  float dist[8];
  #pragma unroll
  for (int i = 0; i < 8; ++i) dist[i] = 1e10f;
  int base = tid * 8;
  int last = 0;
  float4 l0 = sp4[0];            // point 0 (slot 0), broadcast read once
  float lx = l0.x, ly = l0.y, lz = l0.z;
  for (int it = 0; it < M; ++it) {
    int p = it & 1;
    if (tid == 0) fidx[it] = last;
    float best = -INFINITY; int bi = N;
    #pragma unroll
    for (int i = 0; i < 8; ++i) {
      float dx = pt[i].x - lx, dy = pt[i].y - ly, dz = pt[i].z - lz;
      float dx2 = dx * dx, dy2 = dy * dy, dz2 = dz * dz;
      float d = (dx2 + dy2) + dz2;
      float dn = dist[i];
      if (d < dn) dn = d;
      dist[i] = dn;
      if (dn > best) { best = dn; bi = base + i; }  // ascending -> first max in lane kept
    }
    // per-thread coords of its own best point (register select; off critical path)
    float cx = pt[0].x, cy = pt[0].y, cz = pt[0].z;
    #pragma unroll
    for (int i = 1; i < 8; ++i) {
      bool c = (bi == base + i);
      cx = c ? pt[i].x : cx; cy = c ? pt[i].y : cy; cz = c ? pt[i].z : cz;
    }
    // wave argmax: DPP fmax, then DPP imin over candidate indices (min-index among maxima)
    float gmax = wave_fmax(best);
    int cand = (best == gmax) ? bi : 0x7FFFFFFF;
    int wbi = wave_imin(cand);                       // uniform
    if (bi == wbi) { wvc[p * 4 + w] = make_float4(gmax, cx, cy, cz); wis[p * 4 + w] = wbi; }
    __syncthreads();
    // all threads redundantly combine the 4 wave results (waves ascend in index)
    float4 c0 = wvc[p * 4 + 0], c1 = wvc[p * 4 + 1], c2 = wvc[p * 4 + 2], c3 = wvc[p * 4 + 3];
    int i0 = wis[p * 4 + 0], i1 = wis[p * 4 + 1], i2 = wis[p * 4 + 2], i3 = wis[p * 4 + 3];
    float bv = c0.x; int bbi = i0; lx = c0.y; ly = c0.z; lz = c0.w;
    { bool c = (c1.x > bv) || (c1.x == bv && i1 < bbi);
      bv = c ? c1.x : bv; bbi = c ? i1 : bbi; lx = c ? c1.y : lx; ly = c ? c1.z : ly; lz = c ? c1.w : lz; }
    { bool c = (c2.x > bv) || (c2.x == bv && i2 < bbi);
      bv = c ? c2.x : bv; bbi = c ? i2 : bbi; lx = c ? c2.y : lx; ly = c ? c2.z : ly; lz = c ? c2.w : lz; }
    { bool c = (c3.x > bv) || (c3.x == bv && i3 < bbi);
      bv = c ? c3.x : bv; bbi = c ? i3 : bbi; lx = c ? c3.y : lx; ly = c ? c3.z : ly; lz = c ? c3.w : lz; }
    last = bbi;
    // parity: slot p rewritten only in iter it+2, after barrier it+1 -> safe with 1 barrier
  }
  for (int e = tid; e < M; e += 256) fpsIdx[(long)b * M + e] = fidx[e];
  for (int e = tid; e < 3 * M; e += 256) {
    int c = e / M, i = e % M;
    int src = fidx[i];
    float4 ptc = sp4[((src & 7) << 8) | (src >> 3)];
    node1[(long)b * 3 * M + e] = (c == 0) ? ptc.x : (c == 1) ? ptc.y : ptc.z;
  }
}

// ---------------- fused stage-2 knn + FPS.
// R6 post-mortem: co-resident knn waves stole issue slots from the latency-bound fps
// waves (486us fused vs 321us standalone fps). Fix: raise fps waves to priority 1 —
// the SIMD scheduler then issues fps instructions the cycle they're ready; knn waves
// (throughput-bound, always ready) fill the stall cycles. Scheduler hint only; outputs
// bit-identical.
__global__ void knn4fps_kernel(const float* __restrict__ Q, int qStrideB,
                               const float* __restrict__ Xc, int cStrideB,
                               int C, int M, int N, int k, int* __restrict__ idxOut,
                               const float* __restrict__ xyz, int Mf,
                               int* __restrict__ fpsIdx, float* __restrict__ node1) {
  __shared__ __align__(16) char smem[32768 + 2048 + 128 + 32];   // union: knn 32KB | fps 34.9KB
  if (blockIdx.x == 0) {
    __builtin_amdgcn_s_setprio(1);   // fps = latency-bound critical path, prioritize
    fps_body(xyz, N, Mf, fpsIdx, node1, blockIdx.y, smem);
    __builtin_amdgcn_s_setprio(0);
  } else {
    knn4_body<8>(Q, qStrideB, Xc, cStrideB, C, M, N, k, idxOut,
                 blockIdx.y, (blockIdx.x - 1) * 4, smem);
  }
}

// ---------------- gemmPS: one pass computes BOTH halves of the edge-conv weight ----------------
__global__ void gemmPS_kernel(const float* __restrict__ X, int xStrideB, int C, int Np,
                              const float* __restrict__ W, int ldw, int O,
                              float* __restrict__ PtT, float* __restrict__ StT) {
  __shared__ float Wp[16][65];
  __shared__ float Ws[16][65];
  __shared__ float Xt[16][65];
  int b = blockIdx.z;
  int n0 = blockIdx.x * 64, o0 = blockIdx.y * 64;
  int tid = threadIdx.x;
  int to = tid % 16, tn = tid / 16;
  float accP[4][4] = {}, accS[4][4] = {};
  for (int c0 = 0; c0 < C; c0 += 16) {
    for (int e = tid; e < 16 * 64; e += 256) {
      int oo = e / 16, kk = e % 16;
      int c = c0 + kk, o = o0 + oo;
      bool ok = (c < C && o < O);
      Wp[kk][oo] = ok ? W[(long)o * ldw + c] : 0.f;
      Ws[kk][oo] = ok ? W[(long)o * ldw + C + c] : 0.f;
    }
    for (int e = tid; e < 16 * 64; e += 256) {
      int kk = e / 64, nn = e % 64;
      int c = c0 + kk, n = n0 + nn;
      Xt[kk][nn] = (c < C && n < Np) ? X[(long)b * xStrideB + (long)c * Np + n] : 0.f;
    }
    __syncthreads();
    for (int kk = 0; kk < 16; ++kk) {
      float xv[4], wp[4], ws[4];
      for (int i = 0; i < 4; ++i) xv[i] = Xt[kk][tn + 16 * i];
      for (int j = 0; j < 4; ++j) { wp[j] = Wp[kk][to + 16 * j]; ws[j] = Ws[kk][to + 16 * j]; }
      for (int i = 0; i < 4; ++i)
        for (int j = 0; j < 4; ++j) {
          accP[i][j] = fmaf(xv[i], wp[j], accP[i][j]);
          accS[i][j] = fmaf(xv[i], ws[j], accS[i][j]);
        }
    }
    __syncthreads();
  }
  for (int i = 0; i < 4; ++i) {
    int n = n0 + tn + 16 * i;
    if (n >= Np) continue;
    for (int j = 0; j < 4; ++j) {
      int o = o0 + to + 16 * j;
      if (o < O) {
        long off = ((long)b * Np + n) * O + o;
        PtT[off] = accP[i][j];
        StT[off] = accS[i][j];
      }
    }
  }
}

// ---------------- ecfinish ----------------
__global__ void ecfinish_kernel(const float* __restrict__ Pt, const float* __restrict__ St,
                                const int* __restrict__ idx, int k, int O, int Np,
                                const float* __restrict__ g, const float* __restrict__ bb,
                                float* __restrict__ outp, long oStrideB) {
  int b = blockIdx.y;
  int n = blockIdx.x * blockDim.y + threadIdx.y;
  int o = threadIdx.x;
  const float* PtB = Pt + (long)b * Np * O;
  const float* StB = St + (long)b * Np * O;
  const int* ip = idx + ((long)b * Np + n) * k;
  float mx = -INFINITY, mn = INFINITY;
  for (int kk = 0; kk < k; ++kk) {
    float v = PtB[(long)ip[kk] * O + o];
    mx = fmaxf(mx, v); mn = fminf(mn, v);
  }
  float ctrP = PtB[(long)n * O + o];
  float ctrS = StB[(long)n * O + o];
  float gs = g[o] * BN_SCALE;
  float m = (gs >= 0.f) ? mx : mn;
  float h = (ctrS - ctrP + m) * gs + bb[o];
  outp[(long)b * oStrideB + (long)o * Np + n] = h >= 0.f ? h : 0.2f * h;
}

// ---------------- gemm_colmax ----------------
__global__ void gemm_colmax_kernel(const float* __restrict__ X, int xStrideB, int C, int Np,
                                   const float* __restrict__ W, int ldw, int O,
                                   const float* __restrict__ g, const float* __restrict__ bb,
                                   float* __restrict__ partial) {
  __shared__ float Wt[16][65];
  __shared__ float Xt[16][65];
  int b = blockIdx.z;
  int n0 = blockIdx.x * 64, o0 = blockIdx.y * 64;
  int tid = threadIdx.x;
  int to = tid % 16, tn = tid / 16;
  float acc[4][4] = {};
  for (int c0 = 0; c0 < C; c0 += 16) {
    for (int e = tid; e < 16 * 64; e += 256) {
      int oo = e / 16, kk = e % 16;
      int c = c0 + kk, o = o0 + oo;
      Wt[kk][oo] = (c < C && o < O) ? W[(long)o * ldw + c] : 0.f;
    }
    for (int e = tid; e < 16 * 64; e += 256) {
      int kk = e / 64, nn = e % 64;
      int c = c0 + kk, n = n0 + nn;
      Xt[kk][nn] = (c < C && n < Np) ? X[(long)b * xStrideB + (long)c * Np + n] : 0.f;
    }
    __syncthreads();
    for (int kk = 0; kk < 16; ++kk) {
      float xv[4], wv[4];
      for (int i = 0; i < 4; ++i) xv[i] = Xt[kk][tn + 16 * i];
      for (int j = 0; j < 4; ++j) wv[j] = Wt[kk][to + 16 * j];
      for (int i = 0; i < 4; ++i)
        for (int j = 0; j < 4; ++j) acc[i][j] = fmaf(xv[i], wv[j], acc[i][j]);
    }
    __syncthreads();
  }
  float vm[4];
  for (int j = 0; j < 4; ++j) {
    int o = o0 + to + 16 * j;
    float gs = g[o] * BN_SCALE, bo = bb[o];
    float m = -INFINITY;
    for (int i = 0; i < 4; ++i) {
      float h = acc[i][j] * gs + bo;
      h = h >= 0.f ? h : 0.2f * h;
      m = fmaxf(m, h);
    }
    vm[j] = m;
  }
  for (int j = 0; j < 4; ++j) Xt[tn][to + 16 * j] = vm[j];
  __syncthreads();
  for (int s = 8; s > 0; s >>= 1) {
    if (tn < s)
      for (int j = 0; j < 4; ++j)
        Xt[tn][to + 16 * j] = fmaxf(Xt[tn][to + 16 * j], Xt[tn + s][to + 16 * j]);
    __syncthreads();
  }
  if (tn == 0)
    for (int j = 0; j < 4; ++j) {
      int o = o0 + to + 16 * j;
      partial[((long)b * gridDim.x + blockIdx.x) * O + o] = Xt[0][to + 16 * j];
    }
}

// ---------------- xmfill: fused nf1 gather + aggregate gathermax ----------------
__global__ void xmfill_kernel(const float* __restrict__ xt1, int N,
                              const int* __restrict__ fpsI,
                              const int* __restrict__ idxK, int k, int M,
                              float* __restrict__ xm, int B) {
  long t = (long)blockIdx.x * blockDim.x + threadIdx.x;
  long total = (long)B * 128 * M;
  if (t >= total) return;
  int i = (int)(t % M);
  int c = (int)((t / M) % 128);
  int b = (int)(t / ((long)128 * M));
  const float* xb = xt1 + (long)b * 128 * N + (long)c * N;
  float* xmB = xm + (long)b * 256 * M;
  xmB[(long)c * M + i] = xb[fpsI[(long)b * M + i]];
  const int* ip = idxK + ((long)b * M + i) * k;
  float best = -INFINITY;
  for (int kk = 0; kk < k; ++kk) best = fmaxf(best, xb[ip[kk]]);
  xmB[(long)(128 + c) * M + i] = best;
}

// ---------------- head: fused colmax_finish + 3-layer MLP ----------------
__global__ void head_kernel(const float* __restrict__ partA, int NTa,
                            const float* __restrict__ partB, int NTb,
                            const float* __restrict__ Wl1, const float* __restrict__ g6, const float* __restrict__ b6,
                            const float* __restrict__ Wl2, const float* __restrict__ bl2,
                            const float* __restrict__ g7, const float* __restrict__ b7,
                            const float* __restrict__ Wl3, const float* __restrict__ bl3,
                            float* __restrict__ logits) {
  __shared__ float v[2048];
  __shared__ float h1[512];
  __shared__ float h2[256];
  int b = blockIdx.x, tid = threadIdx.x;
  for (int o = tid; o < 1024; o += 256) {
    float m = -INFINITY;
    for (int t = 0; t < NTa; ++t) m = fmaxf(m, partA[((long)b * NTa + t) * 1024 + o]);
    v[o] = m;
    float m2 = -INFINITY;
    for (int t = 0; t < NTb; ++t) m2 = fmaxf(m2, partB[((long)b * NTb + t) * 1024 + o]);
    v[1024 + o] = m2;
  }
  __syncthreads();
  for (int o = tid; o < 512; o += 256) {
    const float* wr = Wl1 + (long)o * 2048;
    float s = 0.f;
    for (int c = 0; c < 2048; c += 4) {
      float4 w4 = *(const float4*)(wr + c);
      s = fmaf(w4.x, v[c], s); s = fmaf(w4.y, v[c + 1], s);
      s = fmaf(w4.z, v[c + 2], s); s = fmaf(w4.w, v[c + 3], s);
    }
    float h = s * (g6[o] * BN_SCALE) + b6[o];
    h1[o] = h >= 0.f ? h : 0.2f * h;
  }
  __syncthreads();
  for (int o = tid; o < 256; o += 256) {
    const float* wr = Wl2 + (long)o * 512;
    float s = 0.f;
    for (int c = 0; c < 512; c += 4) {
      float4 w4 = *(const float4*)(wr + c);
      s = fmaf(w4.x, h1[c], s); s = fmaf(w4.y, h1[c + 1], s);
      s = fmaf(w4.z, h1[c + 2], s); s = fmaf(w4.w, h1[c + 3], s);
    }
    s += bl2[o];
    float h = s * (g7[o] * BN_SCALE) + b7[o];
    h2[o] = h >= 0.f ? h : 0.2f * h;
  }
  __syncthreads();
  if (tid < 40) {
    const float* wr = Wl3 + (long)tid * 256;
    float s = 0.f;
    for (int c = 0; c < 256; ++c) s = fmaf(wr[c], h2[c], s);
    logits[(long)b * 40 + tid] = s + bl3[tid];
  }
}

extern "C" void kernel_launch(void* const* d_in, const int* in_sizes, int n_in,
                              void* d_out, int out_size, void* d_ws, size_t ws_size,
                              hipStream_t stream) {
  const float* x   = (const float*)d_in[0];
  const float* W1  = (const float*)d_in[1];
  const float* g1  = (const float*)d_in[2];
  const float* b1  = (const float*)d_in[3];
  const float* W2  = (const float*)d_in[4];
  const float* g2  = (const float*)d_in[5];
  const float* b2  = (const float*)d_in[6];
  const float* W2m = (const float*)d_in[7];
  const float* g2m = (const float*)d_in[8];
  const float* b2m = (const float*)d_in[9];
  const float* W3  = (const float*)d_in[10];
  const float* g3  = (const float*)d_in[11];
  const float* b3  = (const float*)d_in[12];
  const float* W4  = (const float*)d_in[13];
  const float* g4  = (const float*)d_in[14];
  const float* b4  = (const float*)d_in[15];
  const float* W5  = (const float*)d_in[16];
  const float* g5  = (const float*)d_in[17];
  const float* b5  = (const float*)d_in[18];
  const float* Wl1 = (const float*)d_in[19];
  const float* g6  = (const float*)d_in[20];
  const float* b6  = (const float*)d_in[21];
  const float* Wl2 = (const float*)d_in[22];
  const float* bl2 = (const float*)d_in[23];
  const float* g7  = (const float*)d_in[24];
  const float* b7  = (const float*)d_in[25];
  const float* Wl3 = (const float*)d_in[26];
  const float* bl3 = (const float*)d_in[27];
  float* outF = (float*)d_out;

  const int B = 8, N = 2048, K = 20, M = 512, K2 = 10;

  float* ws    = (float*)d_ws;
  float* xt1   = ws;                               // (B,128,N)
  float* xm    = xt1 + (size_t)B * 128 * N;        // (B,256,M)
  float* xc    = xm  + (size_t)B * 256 * M;        // (B,512,M)
  float* Pt    = xc  + (size_t)B * 512 * M;        // max(B*N*64, B*M*256)
  float* St    = Pt  + (size_t)B * N * 64;
  float* partA = St  + (size_t)B * N * 64;         // (B,32,1024)
  float* partB = partA + (size_t)B * 32 * 1024;    // (B,8,1024)
  int*   idxK  = (int*)(partB + (size_t)B * 8 * 1024);  // (B,N,K)
  int*   fpsI  = idxK + (size_t)B * N * K;         // (B,M)

  float* logits = outF;        // (B,40)
  float* node1  = outF + 320;  // (B,3,M)

  dim3 t256(256);

  // ---- stage 1: knn(xyz) + edge_conv1 -> xt1 ch 0..63
  knn4_kernel<8><<<dim3(N / 4, B), t256, 0, stream>>>(x, 3 * N, x, 3 * N, 3, N, N, K, idxK);
  gemmPS_kernel<<<dim3(N / 64, 1, B), t256, 0, stream>>>(x, 3 * N, 3, N, W1, 6, 64, Pt, St);
  ecfinish_kernel<<<dim3(N / 4, B), dim3(64, 4), 0, stream>>>(Pt, St, idxK, K, 64, N, g1, b1, xt1, (long)128 * N);

  // ---- stage 2: knn(x1) FUSED with FPS (independent work, concurrent; fps at prio 1)
  knn4fps_kernel<<<dim3(1 + N / 4, B), t256, 0, stream>>>(xt1, 128 * N, xt1, 128 * N, 64, N, N, K, idxK,
                                                          x, M, fpsI, node1);
  gemmPS_kernel<<<dim3(N / 64, 1, B), t256, 0, stream>>>(xt1, 128 * N, 64, N, W2, 128, 64, Pt, St);
  ecfinish_kernel<<<dim3(N / 4, B), dim3(64, 4), 0, stream>>>(Pt, St, idxK, K, 64, N, g2, b2,
                                                              xt1 + (size_t)64 * N, (long)128 * N);

  // ---- vf partials
  gemm_colmax_kernel<<<dim3(N / 64, 1024 / 64, B), t256, 0, stream>>>(xt1, 128 * N, 128, N, W2m, 128, 1024,
                                                                      g2m, b2m, partA);

  // ---- aggregate knn (node1 vs xyz), then fused xm fill
  knn4_kernel<8><<<dim3(M / 4, B), t256, 0, stream>>>(node1, 3 * M, x, 3 * N, 3, M, N, K, idxK);
  xmfill_kernel<<<dim3((B * 128 * M + 255) / 256), t256, 0, stream>>>(xt1, N, fpsI, idxK, K, M, xm, B);

  // ---- stage 3: knn(xm) + edge_conv3 -> xc ch 0..255
  knn4_kernel<2><<<dim3(M / 4, B), t256, 0, stream>>>(xm, 256 * M, xm, 256 * M, 256, M, M, K2, idxK);
  gemmPS_kernel<<<dim3(M / 64, 256 / 64, B), t256, 0, stream>>>(xm, 256 * M, 256, M, W3, 512, 256, Pt, St);
  ecfinish_kernel<<<dim3(M, B), dim3(256, 1), 0, stream>>>(Pt, St, idxK, K2, 256, M, g3, b3, xc, (long)512 * M);

  // ---- stage 4: knn(x3) + edge_conv4 -> xc ch 256..511
  knn4_kernel<2><<<dim3(M / 4, B), t256, 0, stream>>>(xc, 512 * M, xc, 512 * M, 256, M, M, K2, idxK);
  gemmPS_kernel<<<dim3(M / 64, 256 / 64, B), t256, 0, stream>>>(xc, 512 * M, 256, M, W4, 512, 256, Pt, St);
  ecfinish_kernel<<<dim3(M, B), dim3(256, 1), 0, stream>>>(Pt, St, idxK, K2, 256, M, g4, b4,
                                                           xc + (size_t)256 * M, (long)512 * M);

  // ---- vs partials
  gemm_colmax_kernel<<<dim3(M / 64, 1024 / 64, B), t256, 0, stream>>>(xc, 512 * M, 512, M, W5, 512, 1024,
                                                                      g5, b5, partB);

  // ---- head (fused colmax_finish + MLP)
  head_kernel<<<dim3(B), t256, 0, stream>>>(partA, N / 64, partB, M / 64,
                                            Wl1, g6, b6, Wl2, bl2, g7, b7, Wl3, bl3, logits);
}

// Round 8
// 1328.751 us; speedup vs baseline: 1.2410x; 1.0921x over previous
//
#include <hip/hip_runtime.h>

#define BN_SCALE 0.9999950000374997f  // 1/sqrt(1+1e-5)

// ---- DPP full-wave reductions (validated in fps/knn since R2/R4) ----
template <int CTRL>
__device__ __forceinline__ float dpp_fmax_step(float v) {
  int xi = __builtin_bit_cast(int, v);
  int ti = __builtin_amdgcn_update_dpp(xi, xi, CTRL, 0xf, 0xf, false);  // invalid lanes -> old(=v)
  return fmaxf(v, __builtin_bit_cast(float, ti));
}
template <int CTRL>
__device__ __forceinline__ int dpp_imin_step(int v) {
  int t = __builtin_amdgcn_update_dpp(v, v, CTRL, 0xf, 0xf, false);    // invalid lanes -> old(=v)
  return (t < v) ? t : v;
}
__device__ __forceinline__ float wave_fmax(float v) {
  v = dpp_fmax_step<0x111>(v);  // row_shr:1
  v = dpp_fmax_step<0x112>(v);  // row_shr:2
  v = dpp_fmax_step<0x114>(v);  // row_shr:4
  v = dpp_fmax_step<0x118>(v);  // row_shr:8
  v = dpp_fmax_step<0x142>(v);  // row_bcast:15
  v = dpp_fmax_step<0x143>(v);  // row_bcast:31
  return __builtin_bit_cast(float, __builtin_amdgcn_readlane(__builtin_bit_cast(int, v), 63));
}
__device__ __forceinline__ int wave_imin(int v) {
  v = dpp_imin_step<0x111>(v);
  v = dpp_imin_step<0x112>(v);
  v = dpp_imin_step<0x114>(v);
  v = dpp_imin_step<0x118>(v);
  v = dpp_imin_step<0x142>(v);
  v = dpp_imin_step<0x143>(v);
  return __builtin_amdgcn_readlane(v, 63);
}

// ---------------- knn4 body (R4 version) as a device function ----------------
template <int R>
__device__ __forceinline__ void knn4_body(const float* __restrict__ Q, int qStrideB,
                                          const float* __restrict__ Xc, int cStrideB,
                                          int C, int M, int N, int k, int* __restrict__ idxOut,
                                          int b, int q0, char* smem) {
  constexpr int NR = 4 * R;                          // values per lane in selection
  float (*negd)[R * 256] = (float (*)[R * 256])smem;
  int tid = threadIdx.x;
  const float* qb = Q + (long)b * qStrideB + q0;     // + c*M walks channels (uniform)
  const float* cb = Xc + (long)b * cStrideB;         // uniform
  float d0[R], d1[R], d2[R], d3[R], sq[R];
  #pragma unroll
  for (int i = 0; i < R; ++i) { d0[i] = d1[i] = d2[i] = d3[i] = sq[i] = 0.f; }
  for (int c = 0; c < C; ++c) {
    float4 q4 = *(const float4*)(qb + (long)c * M);  // uniform -> scalar load
    const float* pc = cb + (long)c * N;              // uniform base
    #pragma unroll
    for (int i = 0; i < R; ++i) {
      float xv = pc[tid + 256 * i];
      sq[i] = fmaf(xv, xv, sq[i]);
      d0[i] = fmaf(q4.x, xv, d0[i]);
      d1[i] = fmaf(q4.y, xv, d1[i]);
      d2[i] = fmaf(q4.z, xv, d2[i]);
      d3[i] = fmaf(q4.w, xv, d3[i]);
    }
  }
  #pragma unroll
  for (int i = 0; i < R; ++i) {
    int m = tid + 256 * i;
    negd[0][m] = 2.f * d0[i] - sq[i];
    negd[1][m] = 2.f * d1[i] - sq[i];
    negd[2][m] = 2.f * d2[i] - sq[i];
    negd[3][m] = 2.f * d3[i] - sq[i];
  }
  __syncthreads();
  int lane = tid & 63, w = tid >> 6;
  const float* row = negd[w];
  int* outp = idxOut + ((long)b * M + (q0 + w)) * k;
  float v[NR];
  #pragma unroll
  for (int i = 0; i < NR; ++i) v[i] = row[lane + 64 * i];   // conflict-free, once
  for (int kk = 0; kk < k; ++kk) {
    float best = -INFINITY; int ib = 0;
    #pragma unroll
    for (int i = 0; i < NR; ++i) {
      bool c = v[i] > best;                 // strict > : first (smallest m) kept on ties
      best = c ? v[i] : best;
      ib = c ? i : ib;
    }
    int bi = (best > -INFINITY) ? (lane + (ib << 6)) : N;   // all-removed lane -> N (orig sem)
    float gmax = wave_fmax(best);
    int cand = (best == gmax) ? bi : 0x7FFFFFFF;
    int big = wave_imin(cand);              // smallest index among global maxima (uniform)
    if (lane == 0) outp[kk] = big;
    int ri = big >> 6;                      // uniform
    bool mine = (lane == (big & 63));
    #pragma unroll
    for (int i = 0; i < NR; ++i)
      if (i == ri) v[i] = mine ? -INFINITY : v[i];          // i==ri uniform -> 1 cndmask
  }
}

template <int R>
__global__ void knn4_kernel(const float* __restrict__ Q, int qStrideB,
                            const float* __restrict__ Xc, int cStrideB,
                            int C, int M, int N, int k, int* __restrict__ idxOut) {
  __shared__ __align__(16) char smem[R * 256 * 4 * 4];
  knn4_body<R>(Q, qStrideB, Xc, cStrideB, C, M, N, k, idxOut,
               blockIdx.y, blockIdx.x * 4, smem);
}

// ---------------- FPS body: 4-wave R2 structure + DPP-imin winner selection.
__device__ __forceinline__ void fps_body(const float* __restrict__ xyz, int N, int M,
                                         int* __restrict__ fpsIdx, float* __restrict__ node1,
                                         int b, char* smem) {
  #pragma clang fp contract(off)
  float4* sp4 = (float4*)smem;                 // 2048 pts: slot (n&7)*256 + (n>>3); 32768 B
  int*    fidx = (int*)(smem + 32768);         // 512 ints; 2048 B
  float4* wvc  = (float4*)(smem + 32768 + 2048);      // [2][4] {gmax,x,y,z}; 128 B
  int*    wis  = (int*)(smem + 32768 + 2048 + 128);   // [2][4]; 32 B
  int tid = threadIdx.x;
  int lane = tid & 63, w = tid >> 6;
  const float* xb = xyz + (long)b * 3 * N;
  for (int n = tid; n < N; n += 256) {
    sp4[((n & 7) << 8) | (n >> 3)] = make_float4(xb[n], xb[N + n], xb[2 * N + n], 0.f);
  }
  __syncthreads();
  float4 pt[8];
  #pragma unroll
  for (int i = 0; i < 8; ++i) pt[i] = sp4[(i << 8) | tid];   // point tid*8+i, in VGPRs
  float dist[8];
  #pragma unroll
  for (int i = 0; i < 8; ++i) dist[i] = 1e10f;
  int base = tid * 8;
  int last = 0;
  float4 l0 = sp4[0];            // point 0 (slot 0), broadcast read once
  float lx = l0.x, ly = l0.y, lz = l0.z;
  for (int it = 0; it < M; ++it) {
    int p = it & 1;
    if (tid == 0) fidx[it] = last;
    float best = -INFINITY; int bi = N;
    #pragma unroll
    for (int i = 0; i < 8; ++i) {
      float dx = pt[i].x - lx, dy = pt[i].y - ly, dz = pt[i].z - lz;
      float dx2 = dx * dx, dy2 = dy * dy, dz2 = dz * dz;
      float d = (dx2 + dy2) + dz2;
      float dn = dist[i];
      if (d < dn) dn = d;
      dist[i] = dn;
      if (dn > best) { best = dn; bi = base + i; }  // ascending -> first max in lane kept
    }
    // per-thread coords of its own best point (register select; off critical path)
    float cx = pt[0].x, cy = pt[0].y, cz = pt[0].z;
    #pragma unroll
    for (int i = 1; i < 8; ++i) {
      bool c = (bi == base + i);
      cx = c ? pt[i].x : cx; cy = c ? pt[i].y : cy; cz = c ? pt[i].z : cz;
    }
    // wave argmax: DPP fmax, then DPP imin over candidate indices (min-index among maxima)
    float gmax = wave_fmax(best);
    int cand = (best == gmax) ? bi : 0x7FFFFFFF;
    int wbi = wave_imin(cand);                       // uniform
    if (bi == wbi) { wvc[p * 4 + w] = make_float4(gmax, cx, cy, cz); wis[p * 4 + w] = wbi; }
    __syncthreads();
    // all threads redundantly combine the 4 wave results (waves ascend in index)
    float4 c0 = wvc[p * 4 + 0], c1 = wvc[p * 4 + 1], c2 = wvc[p * 4 + 2], c3 = wvc[p * 4 + 3];
    int i0 = wis[p * 4 + 0], i1 = wis[p * 4 + 1], i2 = wis[p * 4 + 2], i3 = wis[p * 4 + 3];
    float bv = c0.x; int bbi = i0; lx = c0.y; ly = c0.z; lz = c0.w;
    { bool c = (c1.x > bv) || (c1.x == bv && i1 < bbi);
      bv = c ? c1.x : bv; bbi = c ? i1 : bbi; lx = c ? c1.y : lx; ly = c ? c1.z : ly; lz = c ? c1.w : lz; }
    { bool c = (c2.x > bv) || (c2.x == bv && i2 < bbi);
      bv = c ? c2.x : bv; bbi = c ? i2 : bbi; lx = c ? c2.y : lx; ly = c ? c2.z : ly; lz = c ? c2.w : lz; }
    { bool c = (c3.x > bv) || (c3.x == bv && i3 < bbi);
      bv = c ? c3.x : bv; bbi = c ? i3 : bbi; lx = c ? c3.y : lx; ly = c ? c3.z : ly; lz = c ? c3.w : lz; }
    last = bbi;
    // parity: slot p rewritten only in iter it+2, after barrier it+1 -> safe with 1 barrier
  }
  for (int e = tid; e < M; e += 256) fpsIdx[(long)b * M + e] = fidx[e];
  for (int e = tid; e < 3 * M; e += 256) {
    int c = e / M, i = e % M;
    int src = fidx[i];
    float4 ptc = sp4[((src & 7) << 8) | (src >> 3)];
    node1[(long)b * 3 * M + e] = (c == 0) ? ptc.x : (c == 1) ? ptc.y : ptc.z;
  }
}

// ---------------- fused stage-2 knn + FPS, 1D grid with fps blocks FIRST.
// R7 post-mortem: with grid (513,8), fps blocks sat at linearized positions 0,513,...,3591
// — six of eight queued behind ~2500 knn blocks (1024 resident max) and started ~130us
// late. 1D grid with bids 0..7 = fps puts all fps blocks in the first dispatch wavefront.
__global__ void knn4fps_kernel(const float* __restrict__ Q, int qStrideB,
                               const float* __restrict__ Xc, int cStrideB,
                               int C, int M, int N, int k, int* __restrict__ idxOut,
                               const float* __restrict__ xyz, int Mf, int nQblk, int nB,
                               int* __restrict__ fpsIdx, float* __restrict__ node1) {
  __shared__ __align__(16) char smem[32768 + 2048 + 128 + 32];   // union: knn 32KB | fps 34.9KB
  int bid = blockIdx.x;
  if (bid < nB) {
    __builtin_amdgcn_s_setprio(1);   // fps = latency-bound critical path, prioritize
    fps_body(xyz, N, Mf, fpsIdx, node1, bid, smem);
    __builtin_amdgcn_s_setprio(0);
  } else {
    int e = bid - nB;
    int b = e / nQblk, q0 = (e % nQblk) * 4;
    knn4_body<8>(Q, qStrideB, Xc, cStrideB, C, M, N, k, idxOut, b, q0, smem);
  }
}

// ---------------- gemmPS: one pass computes BOTH halves of the edge-conv weight ----------------
__global__ void gemmPS_kernel(const float* __restrict__ X, int xStrideB, int C, int Np,
                              const float* __restrict__ W, int ldw, int O,
                              float* __restrict__ PtT, float* __restrict__ StT) {
  __shared__ float Wp[16][65];
  __shared__ float Ws[16][65];
  __shared__ float Xt[16][65];
  int b = blockIdx.z;
  int n0 = blockIdx.x * 64, o0 = blockIdx.y * 64;
  int tid = threadIdx.x;
  int to = tid % 16, tn = tid / 16;
  float accP[4][4] = {}, accS[4][4] = {};
  for (int c0 = 0; c0 < C; c0 += 16) {
    for (int e = tid; e < 16 * 64; e += 256) {
      int oo = e / 16, kk = e % 16;
      int c = c0 + kk, o = o0 + oo;
      bool ok = (c < C && o < O);
      Wp[kk][oo] = ok ? W[(long)o * ldw + c] : 0.f;
      Ws[kk][oo] = ok ? W[(long)o * ldw + C + c] : 0.f;
    }
    for (int e = tid; e < 16 * 64; e += 256) {
      int kk = e / 64, nn = e % 64;
      int c = c0 + kk, n = n0 + nn;
      Xt[kk][nn] = (c < C && n < Np) ? X[(long)b * xStrideB + (long)c * Np + n] : 0.f;
    }
    __syncthreads();
    for (int kk = 0; kk < 16; ++kk) {
      float xv[4], wp[4], ws[4];
      for (int i = 0; i < 4; ++i) xv[i] = Xt[kk][tn + 16 * i];
      for (int j = 0; j < 4; ++j) { wp[j] = Wp[kk][to + 16 * j]; ws[j] = Ws[kk][to + 16 * j]; }
      for (int i = 0; i < 4; ++i)
        for (int j = 0; j < 4; ++j) {
          accP[i][j] = fmaf(xv[i], wp[j], accP[i][j]);
          accS[i][j] = fmaf(xv[i], ws[j], accS[i][j]);
        }
    }
    __syncthreads();
  }
  for (int i = 0; i < 4; ++i) {
    int n = n0 + tn + 16 * i;
    if (n >= Np) continue;
    for (int j = 0; j < 4; ++j) {
      int o = o0 + to + 16 * j;
      if (o < O) {
        long off = ((long)b * Np + n) * O + o;
        PtT[off] = accP[i][j];
        StT[off] = accS[i][j];
      }
    }
  }
}

// ---------------- ecfinish ----------------
__global__ void ecfinish_kernel(const float* __restrict__ Pt, const float* __restrict__ St,
                                const int* __restrict__ idx, int k, int O, int Np,
                                const float* __restrict__ g, const float* __restrict__ bb,
                                float* __restrict__ outp, long oStrideB) {
  int b = blockIdx.y;
  int n = blockIdx.x * blockDim.y + threadIdx.y;
  int o = threadIdx.x;
  const float* PtB = Pt + (long)b * Np * O;
  const float* StB = St + (long)b * Np * O;
  const int* ip = idx + ((long)b * Np + n) * k;
  float mx = -INFINITY, mn = INFINITY;
  for (int kk = 0; kk < k; ++kk) {
    float v = PtB[(long)ip[kk] * O + o];
    mx = fmaxf(mx, v); mn = fminf(mn, v);
  }
  float ctrP = PtB[(long)n * O + o];
  float ctrS = StB[(long)n * O + o];
  float gs = g[o] * BN_SCALE;
  float m = (gs >= 0.f) ? mx : mn;
  float h = (ctrS - ctrP + m) * gs + bb[o];
  outp[(long)b * oStrideB + (long)o * Np + n] = h >= 0.f ? h : 0.2f * h;
}

// ---------------- gemm_colmax ----------------
__global__ void gemm_colmax_kernel(const float* __restrict__ X, int xStrideB, int C, int Np,
                                   const float* __restrict__ W, int ldw, int O,
                                   const float* __restrict__ g, const float* __restrict__ bb,
                                   float* __restrict__ partial) {
  __shared__ float Wt[16][65];
  __shared__ float Xt[16][65];
  int b = blockIdx.z;
  int n0 = blockIdx.x * 64, o0 = blockIdx.y * 64;
  int tid = threadIdx.x;
  int to = tid % 16, tn = tid / 16;
  float acc[4][4] = {};
  for (int c0 = 0; c0 < C; c0 += 16) {
    for (int e = tid; e < 16 * 64; e += 256) {
      int oo = e / 16, kk = e % 16;
      int c = c0 + kk, o = o0 + oo;
      Wt[kk][oo] = (c < C && o < O) ? W[(long)o * ldw + c] : 0.f;
    }
    for (int e = tid; e < 16 * 64; e += 256) {
      int kk = e / 64, nn = e % 64;
      int c = c0 + kk, n = n0 + nn;
      Xt[kk][nn] = (c < C && n < Np) ? X[(long)b * xStrideB + (long)c * Np + n] : 0.f;
    }
    __syncthreads();
    for (int kk = 0; kk < 16; ++kk) {
      float xv[4], wv[4];
      for (int i = 0; i < 4; ++i) xv[i] = Xt[kk][tn + 16 * i];
      for (int j = 0; j < 4; ++j) wv[j] = Wt[kk][to + 16 * j];
      for (int i = 0; i < 4; ++i)
        for (int j = 0; j < 4; ++j) acc[i][j] = fmaf(xv[i], wv[j], acc[i][j]);
    }
    __syncthreads();
  }
  float vm[4];
  for (int j = 0; j < 4; ++j) {
    int o = o0 + to + 16 * j;
    float gs = g[o] * BN_SCALE, bo = bb[o];
    float m = -INFINITY;
    for (int i = 0; i < 4; ++i) {
      float h = acc[i][j] * gs + bo;
      h = h >= 0.f ? h : 0.2f * h;
      m = fmaxf(m, h);
    }
    vm[j] = m;
  }
  for (int j = 0; j < 4; ++j) Xt[tn][to + 16 * j] = vm[j];
  __syncthreads();
  for (int s = 8; s > 0; s >>= 1) {
    if (tn < s)
      for (int j = 0; j < 4; ++j)
        Xt[tn][to + 16 * j] = fmaxf(Xt[tn][to + 16 * j], Xt[tn + s][to + 16 * j]);
    __syncthreads();
  }
  if (tn == 0)
    for (int j = 0; j < 4; ++j) {
      int o = o0 + to + 16 * j;
      partial[((long)b * gridDim.x + blockIdx.x) * O + o] = Xt[0][to + 16 * j];
    }
}

// ---------------- xmfill: fused nf1 gather + aggregate gathermax ----------------
__global__ void xmfill_kernel(const float* __restrict__ xt1, int N,
                              const int* __restrict__ fpsI,
                              const int* __restrict__ idxK, int k, int M,
                              float* __restrict__ xm, int B) {
  long t = (long)blockIdx.x * blockDim.x + threadIdx.x;
  long total = (long)B * 128 * M;
  if (t >= total) return;
  int i = (int)(t % M);
  int c = (int)((t / M) % 128);
  int b = (int)(t / ((long)128 * M));
  const float* xb = xt1 + (long)b * 128 * N + (long)c * N;
  float* xmB = xm + (long)b * 256 * M;
  xmB[(long)c * M + i] = xb[fpsI[(long)b * M + i]];
  const int* ip = idxK + ((long)b * M + i) * k;
  float best = -INFINITY;
  for (int kk = 0; kk < k; ++kk) best = fmaxf(best, xb[ip[kk]]);
  xmB[(long)(128 + c) * M + i] = best;
}

// ---------------- head: fused colmax_finish + 3-layer MLP ----------------
__global__ void head_kernel(const float* __restrict__ partA, int NTa,
                            const float* __restrict__ partB, int NTb,
                            const float* __restrict__ Wl1, const float* __restrict__ g6, const float* __restrict__ b6,
                            const float* __restrict__ Wl2, const float* __restrict__ bl2,
                            const float* __restrict__ g7, const float* __restrict__ b7,
                            const float* __restrict__ Wl3, const float* __restrict__ bl3,
                            float* __restrict__ logits) {
  __shared__ float v[2048];
  __shared__ float h1[512];
  __shared__ float h2[256];
  int b = blockIdx.x, tid = threadIdx.x;
  for (int o = tid; o < 1024; o += 256) {
    float m = -INFINITY;
    for (int t = 0; t < NTa; ++t) m = fmaxf(m, partA[((long)b * NTa + t) * 1024 + o]);
    v[o] = m;
    float m2 = -INFINITY;
    for (int t = 0; t < NTb; ++t) m2 = fmaxf(m2, partB[((long)b * NTb + t) * 1024 + o]);
    v[1024 + o] = m2;
  }
  __syncthreads();
  for (int o = tid; o < 512; o += 256) {
    const float* wr = Wl1 + (long)o * 2048;
    float s = 0.f;
    for (int c = 0; c < 2048; c += 4) {
      float4 w4 = *(const float4*)(wr + c);
      s = fmaf(w4.x, v[c], s); s = fmaf(w4.y, v[c + 1], s);
      s = fmaf(w4.z, v[c + 2], s); s = fmaf(w4.w, v[c + 3], s);
    }
    float h = s * (g6[o] * BN_SCALE) + b6[o];
    h1[o] = h >= 0.f ? h : 0.2f * h;
  }
  __syncthreads();
  for (int o = tid; o < 256; o += 256) {
    const float* wr = Wl2 + (long)o * 512;
    float s = 0.f;
    for (int c = 0; c < 512; c += 4) {
      float4 w4 = *(const float4*)(wr + c);
      s = fmaf(w4.x, h1[c], s); s = fmaf(w4.y, h1[c + 1], s);
      s = fmaf(w4.z, h1[c + 2], s); s = fmaf(w4.w, h1[c + 3], s);
    }
    s += bl2[o];
    float h = s * (g7[o] * BN_SCALE) + b7[o];
    h2[o] = h >= 0.f ? h : 0.2f * h;
  }
  __syncthreads();
  if (tid < 40) {
    const float* wr = Wl3 + (long)tid * 256;
    float s = 0.f;
    for (int c = 0; c < 256; ++c) s = fmaf(wr[c], h2[c], s);
    logits[(long)b * 40 + tid] = s + bl3[tid];
  }
}

extern "C" void kernel_launch(void* const* d_in, const int* in_sizes, int n_in,
                              void* d_out, int out_size, void* d_ws, size_t ws_size,
                              hipStream_t stream) {
  const float* x   = (const float*)d_in[0];
  const float* W1  = (const float*)d_in[1];
  const float* g1  = (const float*)d_in[2];
  const float* b1  = (const float*)d_in[3];
  const float* W2  = (const float*)d_in[4];
  const float* g2  = (const float*)d_in[5];
  const float* b2  = (const float*)d_in[6];
  const float* W2m = (const float*)d_in[7];
  const float* g2m = (const float*)d_in[8];
  const float* b2m = (const float*)d_in[9];
  const float* W3  = (const float*)d_in[10];
  const float* g3  = (const float*)d_in[11];
  const float* b3  = (const float*)d_in[12];
  const float* W4  = (const float*)d_in[13];
  const float* g4  = (const float*)d_in[14];
  const float* b4  = (const float*)d_in[15];
  const float* W5  = (const float*)d_in[16];
  const float* g5  = (const float*)d_in[17];
  const float* b5  = (const float*)d_in[18];
  const float* Wl1 = (const float*)d_in[19];
  const float* g6  = (const float*)d_in[20];
  const float* b6  = (const float*)d_in[21];
  const float* Wl2 = (const float*)d_in[22];
  const float* bl2 = (const float*)d_in[23];
  const float* g7  = (const float*)d_in[24];
  const float* b7  = (const float*)d_in[25];
  const float* Wl3 = (const float*)d_in[26];
  const float* bl3 = (const float*)d_in[27];
  float* outF = (float*)d_out;

  const int B = 8, N = 2048, K = 20, M = 512, K2 = 10;

  float* ws    = (float*)d_ws;
  float* xt1   = ws;                               // (B,128,N)
  float* xm    = xt1 + (size_t)B * 128 * N;        // (B,256,M)
  float* xc    = xm  + (size_t)B * 256 * M;        // (B,512,M)
  float* Pt    = xc  + (size_t)B * 512 * M;        // max(B*N*64, B*M*256)
  float* St    = Pt  + (size_t)B * N * 64;
  float* partA = St  + (size_t)B * N * 64;         // (B,32,1024)
  float* partB = partA + (size_t)B * 32 * 1024;    // (B,8,1024)
  int*   idxK  = (int*)(partB + (size_t)B * 8 * 1024);  // (B,N,K)
  int*   fpsI  = idxK + (size_t)B * N * K;         // (B,M)

  float* logits = outF;        // (B,40)
  float* node1  = outF + 320;  // (B,3,M)

  dim3 t256(256);

  // ---- stage 1: knn(xyz) + edge_conv1 -> xt1 ch 0..63
  knn4_kernel<8><<<dim3(N / 4, B), t256, 0, stream>>>(x, 3 * N, x, 3 * N, 3, N, N, K, idxK);
  gemmPS_kernel<<<dim3(N / 64, 1, B), t256, 0, stream>>>(x, 3 * N, 3, N, W1, 6, 64, Pt, St);
  ecfinish_kernel<<<dim3(N / 4, B), dim3(64, 4), 0, stream>>>(Pt, St, idxK, K, 64, N, g1, b1, xt1, (long)128 * N);

  // ---- stage 2: knn(x1) FUSED with FPS; 1D grid, fps blocks 0..7 dispatched first
  knn4fps_kernel<<<dim3(B + (N / 4) * B), t256, 0, stream>>>(xt1, 128 * N, xt1, 128 * N, 64, N, N, K, idxK,
                                                             x, M, N / 4, B, fpsI, node1);
  gemmPS_kernel<<<dim3(N / 64, 1, B), t256, 0, stream>>>(xt1, 128 * N, 64, N, W2, 128, 64, Pt, St);
  ecfinish_kernel<<<dim3(N / 4, B), dim3(64, 4), 0, stream>>>(Pt, St, idxK, K, 64, N, g2, b2,
                                                              xt1 + (size_t)64 * N, (long)128 * N);

  // ---- vf partials
  gemm_colmax_kernel<<<dim3(N / 64, 1024 / 64, B), t256, 0, stream>>>(xt1, 128 * N, 128, N, W2m, 128, 1024,
                                                                      g2m, b2m, partA);

  // ---- aggregate knn (node1 vs xyz), then fused xm fill
  knn4_kernel<8><<<dim3(M / 4, B), t256, 0, stream>>>(node1, 3 * M, x, 3 * N, 3, M, N, K, idxK);
  xmfill_kernel<<<dim3((B * 128 * M + 255) / 256), t256, 0, stream>>>(xt1, N, fpsI, idxK, K, M, xm, B);

  // ---- stage 3: knn(xm) + edge_conv3 -> xc ch 0..255
  knn4_kernel<2><<<dim3(M / 4, B), t256, 0, stream>>>(xm, 256 * M, xm, 256 * M, 256, M, M, K2, idxK);
  gemmPS_kernel<<<dim3(M / 64, 256 / 64, B), t256, 0, stream>>>(xm, 256 * M, 256, M, W3, 512, 256, Pt, St);
  ecfinish_kernel<<<dim3(M, B), dim3(256, 1), 0, stream>>>(Pt, St, idxK, K2, 256, M, g3, b3, xc, (long)512 * M);

  // ---- stage 4: knn(x3) + edge_conv4 -> xc ch 256..511
  knn4_kernel<2><<<dim3(M / 4, B), t256, 0, stream>>>(xc, 512 * M, xc, 512 * M, 256, M, M, K2, idxK);
  gemmPS_kernel<<<dim3(M / 64, 256 / 64, B), t256, 0, stream>>>(xc, 512 * M, 256, M, W4, 512, 256, Pt, St);
  ecfinish_kernel<<<dim3(M, B), dim3(256, 1), 0, stream>>>(Pt, St, idxK, K2, 256, M, g4, b4,
                                                           xc + (size_t)256 * M, (long)512 * M);

  // ---- vs partials
  gemm_colmax_kernel<<<dim3(M / 64, 1024 / 64, B), t256, 0, stream>>>(xc, 512 * M, 512, M, W5, 512, 1024,
                                                                      g5, b5, partB);

  // ---- head (fused colmax_finish + MLP)
  head_kernel<<<dim3(B), t256, 0, stream>>>(partA, N / 64, partB, M / 64,
                                            Wl1, g6, b6, Wl2, bl2, g7, b7, Wl3, bl3, logits);
}

// Round 9
// 1226.558 us; speedup vs baseline: 1.3444x; 1.0833x over previous
//
#include <hip/hip_runtime.h>

#define BN_SCALE 0.9999950000374997f  // 1/sqrt(1+1e-5)

// ---- DPP full-wave reductions (validated in fps/knn since R2/R4) ----
template <int CTRL>
__device__ __forceinline__ float dpp_fmax_step(float v) {
  int xi = __builtin_bit_cast(int, v);
  int ti = __builtin_amdgcn_update_dpp(xi, xi, CTRL, 0xf, 0xf, false);  // invalid lanes -> old(=v)
  return fmaxf(v, __builtin_bit_cast(float, ti));
}
template <int CTRL>
__device__ __forceinline__ int dpp_imin_step(int v) {
  int t = __builtin_amdgcn_update_dpp(v, v, CTRL, 0xf, 0xf, false);    // invalid lanes -> old(=v)
  return (t < v) ? t : v;
}
__device__ __forceinline__ float wave_fmax(float v) {
  v = dpp_fmax_step<0x111>(v);  // row_shr:1
  v = dpp_fmax_step<0x112>(v);  // row_shr:2
  v = dpp_fmax_step<0x114>(v);  // row_shr:4
  v = dpp_fmax_step<0x118>(v);  // row_shr:8
  v = dpp_fmax_step<0x142>(v);  // row_bcast:15
  v = dpp_fmax_step<0x143>(v);  // row_bcast:31
  return __builtin_bit_cast(float, __builtin_amdgcn_readlane(__builtin_bit_cast(int, v), 63));
}
__device__ __forceinline__ int wave_imin(int v) {
  v = dpp_imin_step<0x111>(v);
  v = dpp_imin_step<0x112>(v);
  v = dpp_imin_step<0x114>(v);
  v = dpp_imin_step<0x118>(v);
  v = dpp_imin_step<0x142>(v);
  v = dpp_imin_step<0x143>(v);
  return __builtin_amdgcn_readlane(v, 63);
}

// ---------------- knn4 body (R4 version) ----------------
template <int R>
__device__ __forceinline__ void knn4_body(const float* __restrict__ Q, int qStrideB,
                                          const float* __restrict__ Xc, int cStrideB,
                                          int C, int M, int N, int k, int* __restrict__ idxOut,
                                          int b, int q0, char* smem) {
  constexpr int NR = 4 * R;                          // values per lane in selection
  float (*negd)[R * 256] = (float (*)[R * 256])smem;
  int tid = threadIdx.x;
  const float* qb = Q + (long)b * qStrideB + q0;     // + c*M walks channels (uniform)
  const float* cb = Xc + (long)b * cStrideB;         // uniform
  float d0[R], d1[R], d2[R], d3[R], sq[R];
  #pragma unroll
  for (int i = 0; i < R; ++i) { d0[i] = d1[i] = d2[i] = d3[i] = sq[i] = 0.f; }
  for (int c = 0; c < C; ++c) {
    float4 q4 = *(const float4*)(qb + (long)c * M);  // uniform -> scalar load
    const float* pc = cb + (long)c * N;              // uniform base
    #pragma unroll
    for (int i = 0; i < R; ++i) {
      float xv = pc[tid + 256 * i];
      sq[i] = fmaf(xv, xv, sq[i]);
      d0[i] = fmaf(q4.x, xv, d0[i]);
      d1[i] = fmaf(q4.y, xv, d1[i]);
      d2[i] = fmaf(q4.z, xv, d2[i]);
      d3[i] = fmaf(q4.w, xv, d3[i]);
    }
  }
  #pragma unroll
  for (int i = 0; i < R; ++i) {
    int m = tid + 256 * i;
    negd[0][m] = 2.f * d0[i] - sq[i];
    negd[1][m] = 2.f * d1[i] - sq[i];
    negd[2][m] = 2.f * d2[i] - sq[i];
    negd[3][m] = 2.f * d3[i] - sq[i];
  }
  __syncthreads();
  int lane = tid & 63, w = tid >> 6;
  const float* row = negd[w];
  int* outp = idxOut + ((long)b * M + (q0 + w)) * k;
  float v[NR];
  #pragma unroll
  for (int i = 0; i < NR; ++i) v[i] = row[lane + 64 * i];   // conflict-free, once
  for (int kk = 0; kk < k; ++kk) {
    float best = -INFINITY; int ib = 0;
    #pragma unroll
    for (int i = 0; i < NR; ++i) {
      bool c = v[i] > best;                 // strict > : first (smallest m) kept on ties
      best = c ? v[i] : best;
      ib = c ? i : ib;
    }
    int bi = (best > -INFINITY) ? (lane + (ib << 6)) : N;   // all-removed lane -> N (orig sem)
    float gmax = wave_fmax(best);
    int cand = (best == gmax) ? bi : 0x7FFFFFFF;
    int big = wave_imin(cand);              // smallest index among global maxima (uniform)
    if (lane == 0) outp[kk] = big;
    int ri = big >> 6;                      // uniform
    bool mine = (lane == (big & 63));
    #pragma unroll
    for (int i = 0; i < NR; ++i)
      if (i == ri) v[i] = mine ? -INFINITY : v[i];          // i==ri uniform -> 1 cndmask
  }
}

template <int R>
__global__ void knn4_kernel(const float* __restrict__ Q, int qStrideB,
                            const float* __restrict__ Xc, int cStrideB,
                            int C, int M, int N, int k, int* __restrict__ idxOut) {
  __shared__ __align__(16) char smem[R * 256 * 4 * 4];
  knn4_body<R>(Q, qStrideB, Xc, cStrideB, C, M, N, k, idxOut,
               blockIdx.y, blockIdx.x * 4, smem);
}

// ---------------- gemmPS body ----------------
__device__ __forceinline__ void gemmPS_body(const float* __restrict__ X, int xStrideB, int C, int Np,
                                            const float* __restrict__ W, int ldw, int O,
                                            float* __restrict__ PtT, float* __restrict__ StT,
                                            int b, int n0, int o0, char* smem) {
  float (*Wp)[65] = (float (*)[65])smem;
  float (*Ws)[65] = (float (*)[65])(smem + 4160);
  float (*Xt)[65] = (float (*)[65])(smem + 8320);
  int tid = threadIdx.x;
  int to = tid % 16, tn = tid / 16;
  float accP[4][4] = {}, accS[4][4] = {};
  for (int c0 = 0; c0 < C; c0 += 16) {
    for (int e = tid; e < 16 * 64; e += 256) {
      int oo = e / 16, kk = e % 16;
      int c = c0 + kk, o = o0 + oo;
      bool ok = (c < C && o < O);
      Wp[kk][oo] = ok ? W[(long)o * ldw + c] : 0.f;
      Ws[kk][oo] = ok ? W[(long)o * ldw + C + c] : 0.f;
    }
    for (int e = tid; e < 16 * 64; e += 256) {
      int kk = e / 64, nn = e % 64;
      int c = c0 + kk, n = n0 + nn;
      Xt[kk][nn] = (c < C && n < Np) ? X[(long)b * xStrideB + (long)c * Np + n] : 0.f;
    }
    __syncthreads();
    for (int kk = 0; kk < 16; ++kk) {
      float xv[4], wp[4], ws[4];
      for (int i = 0; i < 4; ++i) xv[i] = Xt[kk][tn + 16 * i];
      for (int j = 0; j < 4; ++j) { wp[j] = Wp[kk][to + 16 * j]; ws[j] = Ws[kk][to + 16 * j]; }
      for (int i = 0; i < 4; ++i)
        for (int j = 0; j < 4; ++j) {
          accP[i][j] = fmaf(xv[i], wp[j], accP[i][j]);
          accS[i][j] = fmaf(xv[i], ws[j], accS[i][j]);
        }
    }
    __syncthreads();
  }
  for (int i = 0; i < 4; ++i) {
    int n = n0 + tn + 16 * i;
    if (n >= Np) continue;
    for (int j = 0; j < 4; ++j) {
      int o = o0 + to + 16 * j;
      if (o < O) {
        long off = ((long)b * Np + n) * O + o;
        PtT[off] = accP[i][j];
        StT[off] = accS[i][j];
      }
    }
  }
}

__global__ void gemmPS_kernel(const float* __restrict__ X, int xStrideB, int C, int Np,
                              const float* __restrict__ W, int ldw, int O,
                              float* __restrict__ PtT, float* __restrict__ StT) {
  __shared__ __align__(16) char smem[3 * 4160];
  gemmPS_body(X, xStrideB, C, Np, W, ldw, O, PtT, StT,
              blockIdx.z, blockIdx.x * 64, blockIdx.y * 64, smem);
}

// ---------------- FPS body, PHASE-split (R8->R9).
// FPS is sequential over 512 iters but its state is tiny: per-thread dist[8] + last.
// PHASE 0: iters [0, M/2) from fresh state; checkpoint dist->ws, last->ws, fidx[0..M/2).
// PHASE 1: rebuild sp4/pt from x (identical), reload dist/last, winner coords via
// sp4[last] broadcast (same expression as R2 original), run [M/2, M), write all outputs.
// Per-iter math verbatim -> fidx/node1 bit-identical to the unsplit version.
template <int PHASE>
__device__ __forceinline__ void fps_body_ph(const float* __restrict__ xyz, int N, int M,
                                            int* __restrict__ fpsIdx, float* __restrict__ node1,
                                            float* __restrict__ distSv, int* __restrict__ lastSv,
                                            int b, char* smem) {
  #pragma clang fp contract(off)
  float4* sp4 = (float4*)smem;                 // 2048 pts: slot (n&7)*256 + (n>>3); 32768 B
  int*    fidx = (int*)(smem + 32768);         // 512 ints; 2048 B
  float4* wvc  = (float4*)(smem + 32768 + 2048);      // [2][4] {gmax,x,y,z}; 128 B
  int*    wis  = (int*)(smem + 32768 + 2048 + 128);   // [2][4]; 32 B
  int tid = threadIdx.x;
  int lane = tid & 63, w = tid >> 6;
  int HALF = M >> 1;
  const float* xb = xyz + (long)b * 3 * N;
  for (int n = tid; n < N; n += 256) {
    sp4[((n & 7) << 8) | (n >> 3)] = make_float4(xb[n], xb[N + n], xb[2 * N + n], 0.f);
  }
  if (PHASE == 1) {
    for (int e = tid; e < HALF; e += 256) fidx[e] = fpsIdx[(long)b * M + e];
  }
  __syncthreads();
  float4 pt[8];
  #pragma unroll
  for (int i = 0; i < 8; ++i) pt[i] = sp4[(i << 8) | tid];   // point tid*8+i, in VGPRs
  float dist[8];
  int last;
  float lx, ly, lz;
  if (PHASE == 0) {
    #pragma unroll
    for (int i = 0; i < 8; ++i) dist[i] = 1e10f;
    last = 0;
    float4 l0 = sp4[0];          // point 0 (slot 0), broadcast read once
    lx = l0.x; ly = l0.y; lz = l0.z;
  } else {
    #pragma unroll
    for (int i = 0; i < 8; ++i) dist[i] = distSv[(long)b * 2048 + i * 256 + tid];
    last = lastSv[b];
    float4 lp = sp4[((last & 7) << 8) | (last >> 3)];   // winner of iter HALF-1
    lx = lp.x; ly = lp.y; lz = lp.z;
  }
  int base = tid * 8;
  int it0 = (PHASE == 0) ? 0 : HALF;
  int it1 = (PHASE == 0) ? HALF : M;
  for (int it = it0; it < it1; ++it) {
    int p = it & 1;
    if (tid == 0) fidx[it] = last;
    float best = -INFINITY; int bi = N;
    #pragma unroll
    for (int i = 0; i < 8; ++i) {
      float dx = pt[i].x - lx, dy = pt[i].y - ly, dz = pt[i].z - lz;
      float dx2 = dx * dx, dy2 = dy * dy, dz2 = dz * dz;
      float d = (dx2 + dy2) + dz2;
      float dn = dist[i];
      if (d < dn) dn = d;
      dist[i] = dn;
      if (dn > best) { best = dn; bi = base + i; }  // ascending -> first max in lane kept
    }
    // per-thread coords of its own best point (register select; off critical path)
    float cx = pt[0].x, cy = pt[0].y, cz = pt[0].z;
    #pragma unroll
    for (int i = 1; i < 8; ++i) {
      bool c = (bi == base + i);
      cx = c ? pt[i].x : cx; cy = c ? pt[i].y : cy; cz = c ? pt[i].z : cz;
    }
    // wave argmax: DPP fmax, then DPP imin over candidate indices (min-index among maxima)
    float gmax = wave_fmax(best);
    int cand = (best == gmax) ? bi : 0x7FFFFFFF;
    int wbi = wave_imin(cand);                       // uniform
    if (bi == wbi) { wvc[p * 4 + w] = make_float4(gmax, cx, cy, cz); wis[p * 4 + w] = wbi; }
    __syncthreads();
    // all threads redundantly combine the 4 wave results (waves ascend in index)
    float4 c0 = wvc[p * 4 + 0], c1 = wvc[p * 4 + 1], c2 = wvc[p * 4 + 2], c3 = wvc[p * 4 + 3];
    int i0 = wis[p * 4 + 0], i1 = wis[p * 4 + 1], i2 = wis[p * 4 + 2], i3 = wis[p * 4 + 3];
    float bv = c0.x; int bbi = i0; lx = c0.y; ly = c0.z; lz = c0.w;
    { bool c = (c1.x > bv) || (c1.x == bv && i1 < bbi);
      bv = c ? c1.x : bv; bbi = c ? i1 : bbi; lx = c ? c1.y : lx; ly = c ? c1.z : ly; lz = c ? c1.w : lz; }
    { bool c = (c2.x > bv) || (c2.x == bv && i2 < bbi);
      bv = c ? c2.x : bv; bbi = c ? i2 : bbi; lx = c ? c2.y : lx; ly = c ? c2.z : ly; lz = c ? c2.w : lz; }
    { bool c = (c3.x > bv) || (c3.x == bv && i3 < bbi);
      bv = c ? c3.x : bv; bbi = c ? i3 : bbi; lx = c ? c3.y : lx; ly = c ? c3.z : ly; lz = c ? c3.w : lz; }
    last = bbi;
    // parity: slot p rewritten only in iter it+2, after barrier it+1 -> safe with 1 barrier
  }
  if (PHASE == 0) {
    for (int e = tid; e < HALF; e += 256) fpsIdx[(long)b * M + e] = fidx[e];
    #pragma unroll
    for (int i = 0; i < 8; ++i) distSv[(long)b * 2048 + i * 256 + tid] = dist[i];
    if (tid == 0) lastSv[b] = last;
  } else {
    for (int e = tid; e < M; e += 256) fpsIdx[(long)b * M + e] = fidx[e];
    for (int e = tid; e < 3 * M; e += 256) {
      int c = e / M, i = e % M;
      int src = fidx[i];
      float4 ptc = sp4[((src & 7) << 8) | (src >> 3)];
      node1[(long)b * 3 * M + e] = (c == 0) ? ptc.x : (c == 1) ? ptc.y : ptc.z;
    }
  }
}

// ---------------- fused {fps-half + knn + gemmPS} kernel, 1D grid, fps first.
// bid 0..nB-1: fps phase; nB..nB+nB*nQblk-1: knn query blocks; rest: gemmPS n-tiles.
__global__ void knnfpsgemm_kernel0(const float* __restrict__ Q, int qStrideB,
                                   const float* __restrict__ Xc, int cStrideB,
                                   int C, int Mq, int N, int k, int* __restrict__ idxOut,
                                   const float* __restrict__ W, int ldw, int O,
                                   float* __restrict__ Pt, float* __restrict__ St,
                                   const float* __restrict__ xyz, int Mf,
                                   int* __restrict__ fpsIdx, float* __restrict__ node1,
                                   float* __restrict__ distSv, int* __restrict__ lastSv,
                                   int nQblk, int nGblk, int nB) {
  __shared__ __align__(16) char smem[32768 + 2048 + 128 + 32];
  int bid = blockIdx.x;
  if (bid < nB) {
    __builtin_amdgcn_s_setprio(1);
    fps_body_ph<0>(xyz, N, Mf, fpsIdx, node1, distSv, lastSv, bid, smem);
    __builtin_amdgcn_s_setprio(0);
  } else if (bid < nB + nB * nQblk) {
    int e = bid - nB;
    knn4_body<8>(Q, qStrideB, Xc, cStrideB, C, Mq, N, k, idxOut,
                 e / nQblk, (e % nQblk) * 4, smem);
  } else {
    int e = bid - nB - nB * nQblk;
    gemmPS_body(Xc, cStrideB, C, N, W, ldw, O, Pt, St,
                e / nGblk, (e % nGblk) * 64, 0, smem);
  }
}

__global__ void knnfpsgemm_kernel1(const float* __restrict__ Q, int qStrideB,
                                   const float* __restrict__ Xc, int cStrideB,
                                   int C, int Mq, int N, int k, int* __restrict__ idxOut,
                                   const float* __restrict__ W, int ldw, int O,
                                   float* __restrict__ Pt, float* __restrict__ St,
                                   const float* __restrict__ xyz, int Mf,
                                   int* __restrict__ fpsIdx, float* __restrict__ node1,
                                   float* __restrict__ distSv, int* __restrict__ lastSv,
                                   int nQblk, int nGblk, int nB) {
  __shared__ __align__(16) char smem[32768 + 2048 + 128 + 32];
  int bid = blockIdx.x;
  if (bid < nB) {
    __builtin_amdgcn_s_setprio(1);
    fps_body_ph<1>(xyz, N, Mf, fpsIdx, node1, distSv, lastSv, bid, smem);
    __builtin_amdgcn_s_setprio(0);
  } else if (bid < nB + nB * nQblk) {
    int e = bid - nB;
    knn4_body<8>(Q, qStrideB, Xc, cStrideB, C, Mq, N, k, idxOut,
                 e / nQblk, (e % nQblk) * 4, smem);
  } else {
    int e = bid - nB - nB * nQblk;
    gemmPS_body(Xc, cStrideB, C, N, W, ldw, O, Pt, St,
                e / nGblk, (e % nGblk) * 64, 0, smem);
  }
}

// ---------------- ecfinish ----------------
__global__ void ecfinish_kernel(const float* __restrict__ Pt, const float* __restrict__ St,
                                const int* __restrict__ idx, int k, int O, int Np,
                                const float* __restrict__ g, const float* __restrict__ bb,
                                float* __restrict__ outp, long oStrideB) {
  int b = blockIdx.y;
  int n = blockIdx.x * blockDim.y + threadIdx.y;
  int o = threadIdx.x;
  const float* PtB = Pt + (long)b * Np * O;
  const float* StB = St + (long)b * Np * O;
  const int* ip = idx + ((long)b * Np + n) * k;
  float mx = -INFINITY, mn = INFINITY;
  for (int kk = 0; kk < k; ++kk) {
    float v = PtB[(long)ip[kk] * O + o];
    mx = fmaxf(mx, v); mn = fminf(mn, v);
  }
  float ctrP = PtB[(long)n * O + o];
  float ctrS = StB[(long)n * O + o];
  float gs = g[o] * BN_SCALE;
  float m = (gs >= 0.f) ? mx : mn;
  float h = (ctrS - ctrP + m) * gs + bb[o];
  outp[(long)b * oStrideB + (long)o * Np + n] = h >= 0.f ? h : 0.2f * h;
}

// ---------------- gemm_colmax ----------------
__global__ void gemm_colmax_kernel(const float* __restrict__ X, int xStrideB, int C, int Np,
                                   const float* __restrict__ W, int ldw, int O,
                                   const float* __restrict__ g, const float* __restrict__ bb,
                                   float* __restrict__ partial) {
  __shared__ float Wt[16][65];
  __shared__ float Xt[16][65];
  int b = blockIdx.z;
  int n0 = blockIdx.x * 64, o0 = blockIdx.y * 64;
  int tid = threadIdx.x;
  int to = tid % 16, tn = tid / 16;
  float acc[4][4] = {};
  for (int c0 = 0; c0 < C; c0 += 16) {
    for (int e = tid; e < 16 * 64; e += 256) {
      int oo = e / 16, kk = e % 16;
      int c = c0 + kk, o = o0 + oo;
      Wt[kk][oo] = (c < C && o < O) ? W[(long)o * ldw + c] : 0.f;
    }
    for (int e = tid; e < 16 * 64; e += 256) {
      int kk = e / 64, nn = e % 64;
      int c = c0 + kk, n = n0 + nn;
      Xt[kk][nn] = (c < C && n < Np) ? X[(long)b * xStrideB + (long)c * Np + n] : 0.f;
    }
    __syncthreads();
    for (int kk = 0; kk < 16; ++kk) {
      float xv[4], wv[4];
      for (int i = 0; i < 4; ++i) xv[i] = Xt[kk][tn + 16 * i];
      for (int j = 0; j < 4; ++j) wv[j] = Wt[kk][to + 16 * j];
      for (int i = 0; i < 4; ++i)
        for (int j = 0; j < 4; ++j) acc[i][j] = fmaf(xv[i], wv[j], acc[i][j]);
    }
    __syncthreads();
  }
  float vm[4];
  for (int j = 0; j < 4; ++j) {
    int o = o0 + to + 16 * j;
    float gs = g[o] * BN_SCALE, bo = bb[o];
    float m = -INFINITY;
    for (int i = 0; i < 4; ++i) {
      float h = acc[i][j] * gs + bo;
      h = h >= 0.f ? h : 0.2f * h;
      m = fmaxf(m, h);
    }
    vm[j] = m;
  }
  for (int j = 0; j < 4; ++j) Xt[tn][to + 16 * j] = vm[j];
  __syncthreads();
  for (int s = 8; s > 0; s >>= 1) {
    if (tn < s)
      for (int j = 0; j < 4; ++j)
        Xt[tn][to + 16 * j] = fmaxf(Xt[tn][to + 16 * j], Xt[tn + s][to + 16 * j]);
    __syncthreads();
  }
  if (tn == 0)
    for (int j = 0; j < 4; ++j) {
      int o = o0 + to + 16 * j;
      partial[((long)b * gridDim.x + blockIdx.x) * O + o] = Xt[0][to + 16 * j];
    }
}

// ---------------- xmfill: fused nf1 gather + aggregate gathermax ----------------
__global__ void xmfill_kernel(const float* __restrict__ xt1, int N,
                              const int* __restrict__ fpsI,
                              const int* __restrict__ idxK, int k, int M,
                              float* __restrict__ xm, int B) {
  long t = (long)blockIdx.x * blockDim.x + threadIdx.x;
  long total = (long)B * 128 * M;
  if (t >= total) return;
  int i = (int)(t % M);
  int c = (int)((t / M) % 128);
  int b = (int)(t / ((long)128 * M));
  const float* xb = xt1 + (long)b * 128 * N + (long)c * N;
  float* xmB = xm + (long)b * 256 * M;
  xmB[(long)c * M + i] = xb[fpsI[(long)b * M + i]];
  const int* ip = idxK + ((long)b * M + i) * k;
  float best = -INFINITY;
  for (int kk = 0; kk < k; ++kk) best = fmaxf(best, xb[ip[kk]]);
  xmB[(long)(128 + c) * M + i] = best;
}

// ---------------- head: fused colmax_finish + 3-layer MLP ----------------
__global__ void head_kernel(const float* __restrict__ partA, int NTa,
                            const float* __restrict__ partB, int NTb,
                            const float* __restrict__ Wl1, const float* __restrict__ g6, const float* __restrict__ b6,
                            const float* __restrict__ Wl2, const float* __restrict__ bl2,
                            const float* __restrict__ g7, const float* __restrict__ b7,
                            const float* __restrict__ Wl3, const float* __restrict__ bl3,
                            float* __restrict__ logits) {
  __shared__ float v[2048];
  __shared__ float h1[512];
  __shared__ float h2[256];
  int b = blockIdx.x, tid = threadIdx.x;
  for (int o = tid; o < 1024; o += 256) {
    float m = -INFINITY;
    for (int t = 0; t < NTa; ++t) m = fmaxf(m, partA[((long)b * NTa + t) * 1024 + o]);
    v[o] = m;
    float m2 = -INFINITY;
    for (int t = 0; t < NTb; ++t) m2 = fmaxf(m2, partB[((long)b * NTb + t) * 1024 + o]);
    v[1024 + o] = m2;
  }
  __syncthreads();
  for (int o = tid; o < 512; o += 256) {
    const float* wr = Wl1 + (long)o * 2048;
    float s = 0.f;
    for (int c = 0; c < 2048; c += 4) {
      float4 w4 = *(const float4*)(wr + c);
      s = fmaf(w4.x, v[c], s); s = fmaf(w4.y, v[c + 1], s);
      s = fmaf(w4.z, v[c + 2], s); s = fmaf(w4.w, v[c + 3], s);
    }
    float h = s * (g6[o] * BN_SCALE) + b6[o];
    h1[o] = h >= 0.f ? h : 0.2f * h;
  }
  __syncthreads();
  for (int o = tid; o < 256; o += 256) {
    const float* wr = Wl2 + (long)o * 512;
    float s = 0.f;
    for (int c = 0; c < 512; c += 4) {
      float4 w4 = *(const float4*)(wr + c);
      s = fmaf(w4.x, h1[c], s); s = fmaf(w4.y, h1[c + 1], s);
      s = fmaf(w4.z, h1[c + 2], s); s = fmaf(w4.w, h1[c + 3], s);
    }
    s += bl2[o];
    float h = s * (g7[o] * BN_SCALE) + b7[o];
    h2[o] = h >= 0.f ? h : 0.2f * h;
  }
  __syncthreads();
  if (tid < 40) {
    const float* wr = Wl3 + (long)tid * 256;
    float s = 0.f;
    for (int c = 0; c < 256; ++c) s = fmaf(wr[c], h2[c], s);
    logits[(long)b * 40 + tid] = s + bl3[tid];
  }
}

extern "C" void kernel_launch(void* const* d_in, const int* in_sizes, int n_in,
                              void* d_out, int out_size, void* d_ws, size_t ws_size,
                              hipStream_t stream) {
  const float* x   = (const float*)d_in[0];
  const float* W1  = (const float*)d_in[1];
  const float* g1  = (const float*)d_in[2];
  const float* b1  = (const float*)d_in[3];
  const float* W2  = (const float*)d_in[4];
  const float* g2  = (const float*)d_in[5];
  const float* b2  = (const float*)d_in[6];
  const float* W2m = (const float*)d_in[7];
  const float* g2m = (const float*)d_in[8];
  const float* b2m = (const float*)d_in[9];
  const float* W3  = (const float*)d_in[10];
  const float* g3  = (const float*)d_in[11];
  const float* b3  = (const float*)d_in[12];
  const float* W4  = (const float*)d_in[13];
  const float* g4  = (const float*)d_in[14];
  const float* b4  = (const float*)d_in[15];
  const float* W5  = (const float*)d_in[16];
  const float* g5  = (const float*)d_in[17];
  const float* b5  = (const float*)d_in[18];
  const float* Wl1 = (const float*)d_in[19];
  const float* g6  = (const float*)d_in[20];
  const float* b6  = (const float*)d_in[21];
  const float* Wl2 = (const float*)d_in[22];
  const float* bl2 = (const float*)d_in[23];
  const float* g7  = (const float*)d_in[24];
  const float* b7  = (const float*)d_in[25];
  const float* Wl3 = (const float*)d_in[26];
  const float* bl3 = (const float*)d_in[27];
  float* outF = (float*)d_out;

  const int B = 8, N = 2048, K = 20, M = 512, K2 = 10;

  float* ws    = (float*)d_ws;
  float* xt1   = ws;                               // (B,128,N)
  float* xm    = xt1 + (size_t)B * 128 * N;        // (B,256,M)
  float* xc    = xm  + (size_t)B * 256 * M;        // (B,512,M)
  float* Pt    = xc  + (size_t)B * 512 * M;        // max(B*N*64, B*M*256)
  float* St    = Pt  + (size_t)B * N * 64;
  float* partA = St  + (size_t)B * N * 64;         // (B,32,1024)
  float* partB = partA + (size_t)B * 32 * 1024;    // (B,8,1024)
  int*   idxK  = (int*)(partB + (size_t)B * 8 * 1024);  // (B,N,K)
  int*   fpsI  = idxK + (size_t)B * N * K;         // (B,M)
  float* fpsDist = (float*)(fpsI + (size_t)B * M); // (B,2048) fps checkpoint dists
  int*   fpsLast = (int*)(fpsDist + (size_t)B * 2048);  // (B)

  float* logits = outF;        // (B,40)
  float* node1  = outF + 320;  // (B,3,M)

  dim3 t256(256);
  const int nQblk = N / 4;     // 512 knn query-blocks per batch
  const int nGblk = N / 64;    // 32 gemmPS n-tiles per batch
  const int nFused = B + B * nQblk + B * nGblk;

  // ---- stage 1 FUSED: fps phase-0 + knn(xyz) + gemmPS1 (all depend only on x)
  knnfpsgemm_kernel0<<<dim3(nFused), t256, 0, stream>>>(
      x, 3 * N, x, 3 * N, 3, N, N, K, idxK,
      W1, 6, 64, Pt, St,
      x, M, fpsI, node1, fpsDist, fpsLast, nQblk, nGblk, B);
  ecfinish_kernel<<<dim3(N / 4, B), dim3(64, 4), 0, stream>>>(Pt, St, idxK, K, 64, N, g1, b1, xt1, (long)128 * N);

  // ---- stage 2 FUSED: fps phase-1 + knn(x1) + gemmPS2 (knn/gemm read stage-1 xt1)
  knnfpsgemm_kernel1<<<dim3(nFused), t256, 0, stream>>>(
      xt1, 128 * N, xt1, 128 * N, 64, N, N, K, idxK,
      W2, 128, 64, Pt, St,
      x, M, fpsI, node1, fpsDist, fpsLast, nQblk, nGblk, B);
  ecfinish_kernel<<<dim3(N / 4, B), dim3(64, 4), 0, stream>>>(Pt, St, idxK, K, 64, N, g2, b2,
                                                              xt1 + (size_t)64 * N, (long)128 * N);

  // ---- vf partials
  gemm_colmax_kernel<<<dim3(N / 64, 1024 / 64, B), t256, 0, stream>>>(xt1, 128 * N, 128, N, W2m, 128, 1024,
                                                                      g2m, b2m, partA);

  // ---- aggregate knn (node1 vs xyz), then fused xm fill
  knn4_kernel<8><<<dim3(M / 4, B), t256, 0, stream>>>(node1, 3 * M, x, 3 * N, 3, M, N, K, idxK);
  xmfill_kernel<<<dim3((B * 128 * M + 255) / 256), t256, 0, stream>>>(xt1, N, fpsI, idxK, K, M, xm, B);

  // ---- stage 3: knn(xm) + edge_conv3 -> xc ch 0..255
  knn4_kernel<2><<<dim3(M / 4, B), t256, 0, stream>>>(xm, 256 * M, xm, 256 * M, 256, M, M, K2, idxK);
  gemmPS_kernel<<<dim3(M / 64, 256 / 64, B), t256, 0, stream>>>(xm, 256 * M, 256, M, W3, 512, 256, Pt, St);
  ecfinish_kernel<<<dim3(M, B), dim3(256, 1), 0, stream>>>(Pt, St, idxK, K2, 256, M, g3, b3, xc, (long)512 * M);

  // ---- stage 4: knn(x3) + edge_conv4 -> xc ch 256..511
  knn4_kernel<2><<<dim3(M / 4, B), t256, 0, stream>>>(xc, 512 * M, xc, 512 * M, 256, M, M, K2, idxK);
  gemmPS_kernel<<<dim3(M / 64, 256 / 64, B), t256, 0, stream>>>(xc, 512 * M, 256, M, W4, 512, 256, Pt, St);
  ecfinish_kernel<<<dim3(M, B), dim3(256, 1), 0, stream>>>(Pt, St, idxK, K2, 256, M, g4, b4,
                                                           xc + (size_t)256 * M, (long)512 * M);

  // ---- vs partials
  gemm_colmax_kernel<<<dim3(M / 64, 1024 / 64, B), t256, 0, stream>>>(xc, 512 * M, 512, M, W5, 512, 1024,
                                                                      g5, b5, partB);

  // ---- head (fused colmax_finish + MLP)
  head_kernel<<<dim3(B), t256, 0, stream>>>(partA, N / 64, partB, M / 64,
                                            Wl1, g6, b6, Wl2, bl2, g7, b7, Wl3, bl3, logits);
}

// Round 10
// 1216.788 us; speedup vs baseline: 1.3552x; 1.0080x over previous
//
#include <hip/hip_runtime.h>

#define BN_SCALE 0.9999950000374997f  // 1/sqrt(1+1e-5)

// ---- DPP full-wave reductions (validated in fps/knn since R2/R4) ----
template <int CTRL>
__device__ __forceinline__ float dpp_fmax_step(float v) {
  int xi = __builtin_bit_cast(int, v);
  int ti = __builtin_amdgcn_update_dpp(xi, xi, CTRL, 0xf, 0xf, false);  // invalid lanes -> old(=v)
  return fmaxf(v, __builtin_bit_cast(float, ti));
}
template <int CTRL>
__device__ __forceinline__ int dpp_imin_step(int v) {
  int t = __builtin_amdgcn_update_dpp(v, v, CTRL, 0xf, 0xf, false);    // invalid lanes -> old(=v)
  return (t < v) ? t : v;
}
__device__ __forceinline__ float wave_fmax(float v) {
  v = dpp_fmax_step<0x111>(v);
  v = dpp_fmax_step<0x112>(v);
  v = dpp_fmax_step<0x114>(v);
  v = dpp_fmax_step<0x118>(v);
  v = dpp_fmax_step<0x142>(v);
  v = dpp_fmax_step<0x143>(v);
  return __builtin_bit_cast(float, __builtin_amdgcn_readlane(__builtin_bit_cast(int, v), 63));
}
__device__ __forceinline__ int wave_imin(int v) {
  v = dpp_imin_step<0x111>(v);
  v = dpp_imin_step<0x112>(v);
  v = dpp_imin_step<0x114>(v);
  v = dpp_imin_step<0x118>(v);
  v = dpp_imin_step<0x142>(v);
  v = dpp_imin_step<0x143>(v);
  return __builtin_amdgcn_readlane(v, 63);
}

// ---------------- knn4 body ----------------
template <int R>
__device__ __forceinline__ void knn4_body(const float* __restrict__ Q, int qStrideB,
                                          const float* __restrict__ Xc, int cStrideB,
                                          int C, int M, int N, int k, int* __restrict__ idxOut,
                                          int b, int q0, char* smem) {
  constexpr int NR = 4 * R;
  float (*negd)[R * 256] = (float (*)[R * 256])smem;
  int tid = threadIdx.x;
  const float* qb = Q + (long)b * qStrideB + q0;
  const float* cb = Xc + (long)b * cStrideB;
  float d0[R], d1[R], d2[R], d3[R], sq[R];
  #pragma unroll
  for (int i = 0; i < R; ++i) { d0[i] = d1[i] = d2[i] = d3[i] = sq[i] = 0.f; }
  for (int c = 0; c < C; ++c) {
    float4 q4 = *(const float4*)(qb + (long)c * M);  // uniform -> scalar load
    const float* pc = cb + (long)c * N;
    #pragma unroll
    for (int i = 0; i < R; ++i) {
      float xv = pc[tid + 256 * i];
      sq[i] = fmaf(xv, xv, sq[i]);
      d0[i] = fmaf(q4.x, xv, d0[i]);
      d1[i] = fmaf(q4.y, xv, d1[i]);
      d2[i] = fmaf(q4.z, xv, d2[i]);
      d3[i] = fmaf(q4.w, xv, d3[i]);
    }
  }
  #pragma unroll
  for (int i = 0; i < R; ++i) {
    int m = tid + 256 * i;
    negd[0][m] = 2.f * d0[i] - sq[i];
    negd[1][m] = 2.f * d1[i] - sq[i];
    negd[2][m] = 2.f * d2[i] - sq[i];
    negd[3][m] = 2.f * d3[i] - sq[i];
  }
  __syncthreads();
  int lane = tid & 63, w = tid >> 6;
  const float* row = negd[w];
  int* outp = idxOut + ((long)b * M + (q0 + w)) * k;
  float v[NR];
  #pragma unroll
  for (int i = 0; i < NR; ++i) v[i] = row[lane + 64 * i];
  for (int kk = 0; kk < k; ++kk) {
    float best = -INFINITY; int ib = 0;
    #pragma unroll
    for (int i = 0; i < NR; ++i) {
      bool c = v[i] > best;                 // strict > : first (smallest m) kept on ties
      best = c ? v[i] : best;
      ib = c ? i : ib;
    }
    int bi = (best > -INFINITY) ? (lane + (ib << 6)) : N;
    float gmax = wave_fmax(best);
    int cand = (best == gmax) ? bi : 0x7FFFFFFF;
    int big = wave_imin(cand);
    if (lane == 0) outp[kk] = big;
    int ri = big >> 6;
    bool mine = (lane == (big & 63));
    #pragma unroll
    for (int i = 0; i < NR; ++i)
      if (i == ri) v[i] = mine ? -INFINITY : v[i];
  }
}

template <int R>
__global__ void knn4_kernel(const float* __restrict__ Q, int qStrideB,
                            const float* __restrict__ Xc, int cStrideB,
                            int C, int M, int N, int k, int* __restrict__ idxOut) {
  __shared__ __align__(16) char smem[R * 256 * 4 * 4];
  knn4_body<R>(Q, qStrideB, Xc, cStrideB, C, M, N, k, idxOut,
               blockIdx.y, blockIdx.x * 4, smem);
}

// ---------------- gemmPS body ----------------
__device__ __forceinline__ void gemmPS_body(const float* __restrict__ X, int xStrideB, int C, int Np,
                                            const float* __restrict__ W, int ldw, int O,
                                            float* __restrict__ PtT, float* __restrict__ StT,
                                            int b, int n0, int o0, char* smem) {
  float (*Wp)[65] = (float (*)[65])smem;
  float (*Ws)[65] = (float (*)[65])(smem + 4160);
  float (*Xt)[65] = (float (*)[65])(smem + 8320);
  int tid = threadIdx.x;
  int to = tid % 16, tn = tid / 16;
  float accP[4][4] = {}, accS[4][4] = {};
  for (int c0 = 0; c0 < C; c0 += 16) {
    for (int e = tid; e < 16 * 64; e += 256) {
      int oo = e / 16, kk = e % 16;
      int c = c0 + kk, o = o0 + oo;
      bool ok = (c < C && o < O);
      Wp[kk][oo] = ok ? W[(long)o * ldw + c] : 0.f;
      Ws[kk][oo] = ok ? W[(long)o * ldw + C + c] : 0.f;
    }
    for (int e = tid; e < 16 * 64; e += 256) {
      int kk = e / 64, nn = e % 64;
      int c = c0 + kk, n = n0 + nn;
      Xt[kk][nn] = (c < C && n < Np) ? X[(long)b * xStrideB + (long)c * Np + n] : 0.f;
    }
    __syncthreads();
    for (int kk = 0; kk < 16; ++kk) {
      float xv[4], wp[4], ws[4];
      for (int i = 0; i < 4; ++i) xv[i] = Xt[kk][tn + 16 * i];
      for (int j = 0; j < 4; ++j) { wp[j] = Wp[kk][to + 16 * j]; ws[j] = Ws[kk][to + 16 * j]; }
      for (int i = 0; i < 4; ++i)
        for (int j = 0; j < 4; ++j) {
          accP[i][j] = fmaf(xv[i], wp[j], accP[i][j]);
          accS[i][j] = fmaf(xv[i], ws[j], accS[i][j]);
        }
    }
    __syncthreads();
  }
  for (int i = 0; i < 4; ++i) {
    int n = n0 + tn + 16 * i;
    if (n >= Np) continue;
    for (int j = 0; j < 4; ++j) {
      int o = o0 + to + 16 * j;
      if (o < O) {
        long off = ((long)b * Np + n) * O + o;
        PtT[off] = accP[i][j];
        StT[off] = accS[i][j];
      }
    }
  }
}

// ---------------- ecfinish body (O=64 flat-256 variant) + standalone kernel ----------------
__device__ __forceinline__ void ecfinish_body64(const float* __restrict__ Pt, const float* __restrict__ St,
                                                const int* __restrict__ idx, int k, int O, int Np,
                                                const float* __restrict__ g, const float* __restrict__ bb,
                                                float* __restrict__ outp, long oStrideB,
                                                int b, int blk) {
  int tid = threadIdx.x;
  int o = tid & 63;
  int n = blk * 4 + (tid >> 6);
  const float* PtB = Pt + (long)b * Np * O;
  const float* StB = St + (long)b * Np * O;
  const int* ip = idx + ((long)b * Np + n) * k;
  float mx = -INFINITY, mn = INFINITY;
  for (int kk = 0; kk < k; ++kk) {
    float v = PtB[(long)ip[kk] * O + o];
    mx = fmaxf(mx, v); mn = fminf(mn, v);
  }
  float ctrP = PtB[(long)n * O + o];
  float ctrS = StB[(long)n * O + o];
  float gs = g[o] * BN_SCALE;
  float m = (gs >= 0.f) ? mx : mn;
  float h = (ctrS - ctrP + m) * gs + bb[o];
  outp[(long)b * oStrideB + (long)o * Np + n] = h >= 0.f ? h : 0.2f * h;
}

__global__ void ecfinish_kernel(const float* __restrict__ Pt, const float* __restrict__ St,
                                const int* __restrict__ idx, int k, int O, int Np,
                                const float* __restrict__ g, const float* __restrict__ bb,
                                float* __restrict__ outp, long oStrideB) {
  int b = blockIdx.y;
  int n = blockIdx.x * blockDim.y + threadIdx.y;
  int o = threadIdx.x;
  const float* PtB = Pt + (long)b * Np * O;
  const float* StB = St + (long)b * Np * O;
  const int* ip = idx + ((long)b * Np + n) * k;
  float mx = -INFINITY, mn = INFINITY;
  for (int kk = 0; kk < k; ++kk) {
    float v = PtB[(long)ip[kk] * O + o];
    mx = fmaxf(mx, v); mn = fminf(mn, v);
  }
  float ctrP = PtB[(long)n * O + o];
  float ctrS = StB[(long)n * O + o];
  float gs = g[o] * BN_SCALE;
  float m = (gs >= 0.f) ? mx : mn;
  float h = (ctrS - ctrP + m) * gs + bb[o];
  outp[(long)b * oStrideB + (long)o * Np + n] = h >= 0.f ? h : 0.2f * h;
}

// ---------------- gemm_colmax body + standalone ----------------
__device__ __forceinline__ void gemm_colmax_body(const float* __restrict__ X, int xStrideB, int C, int Np,
                                                 const float* __restrict__ W, int ldw, int O,
                                                 const float* __restrict__ g, const float* __restrict__ bb,
                                                 float* __restrict__ partial,
                                                 int b, int n0, int o0, int nt, int nNT, char* smem) {
  float (*Wt)[65] = (float (*)[65])smem;
  float (*Xt)[65] = (float (*)[65])(smem + 4160);
  int tid = threadIdx.x;
  int to = tid % 16, tn = tid / 16;
  float acc[4][4] = {};
  for (int c0 = 0; c0 < C; c0 += 16) {
    for (int e = tid; e < 16 * 64; e += 256) {
      int oo = e / 16, kk = e % 16;
      int c = c0 + kk, o = o0 + oo;
      Wt[kk][oo] = (c < C && o < O) ? W[(long)o * ldw + c] : 0.f;
    }
    for (int e = tid; e < 16 * 64; e += 256) {
      int kk = e / 64, nn = e % 64;
      int c = c0 + kk, n = n0 + nn;
      Xt[kk][nn] = (c < C && n < Np) ? X[(long)b * xStrideB + (long)c * Np + n] : 0.f;
    }
    __syncthreads();
    for (int kk = 0; kk < 16; ++kk) {
      float xv[4], wv[4];
      for (int i = 0; i < 4; ++i) xv[i] = Xt[kk][tn + 16 * i];
      for (int j = 0; j < 4; ++j) wv[j] = Wt[kk][to + 16 * j];
      for (int i = 0; i < 4; ++i)
        for (int j = 0; j < 4; ++j) acc[i][j] = fmaf(xv[i], wv[j], acc[i][j]);
    }
    __syncthreads();
  }
  float vm[4];
  for (int j = 0; j < 4; ++j) {
    int o = o0 + to + 16 * j;
    float gs = g[o] * BN_SCALE, bo = bb[o];
    float m = -INFINITY;
    for (int i = 0; i < 4; ++i) {
      float h = acc[i][j] * gs + bo;
      h = h >= 0.f ? h : 0.2f * h;
      m = fmaxf(m, h);
    }
    vm[j] = m;
  }
  for (int j = 0; j < 4; ++j) Xt[tn][to + 16 * j] = vm[j];
  __syncthreads();
  for (int s = 8; s > 0; s >>= 1) {
    if (tn < s)
      for (int j = 0; j < 4; ++j)
        Xt[tn][to + 16 * j] = fmaxf(Xt[tn][to + 16 * j], Xt[tn + s][to + 16 * j]);
    __syncthreads();
  }
  if (tn == 0)
    for (int j = 0; j < 4; ++j) {
      int o = o0 + to + 16 * j;
      partial[((long)b * nNT + nt) * O + o] = Xt[0][to + 16 * j];
    }
}

__global__ void gemm_colmax_kernel(const float* __restrict__ X, int xStrideB, int C, int Np,
                                   const float* __restrict__ W, int ldw, int O,
                                   const float* __restrict__ g, const float* __restrict__ bb,
                                   float* __restrict__ partial) {
  __shared__ __align__(16) char smem[2 * 4160];
  gemm_colmax_body(X, xStrideB, C, Np, W, ldw, O, g, bb, partial,
                   blockIdx.z, blockIdx.x * 64, blockIdx.y * 64, blockIdx.x, gridDim.x, smem);
}

// ---------------- xmfill body ----------------
__device__ __forceinline__ void xmfill_body(const float* __restrict__ xt1, int N,
                                            const int* __restrict__ fpsI,
                                            const int* __restrict__ idxA, int k, int M,
                                            float* __restrict__ xm, int xe) {
  long t = (long)xe * 256 + threadIdx.x;
  int i = (int)(t % M);
  int c = (int)((t / M) % 128);
  int b = (int)(t / ((long)128 * M));
  const float* xb = xt1 + (long)b * 128 * N + (long)c * N;
  float* xmB = xm + (long)b * 256 * M;
  xmB[(long)c * M + i] = xb[fpsI[(long)b * M + i]];
  const int* ip = idxA + ((long)b * M + i) * k;
  float best = -INFINITY;
  for (int kk = 0; kk < k; ++kk) best = fmaxf(best, xb[ip[kk]]);
  xmB[(long)(128 + c) * M + i] = best;
}

// ---------------- FPS body, PHASE-split (unchanged from R9) ----------------
template <int PHASE>
__device__ __forceinline__ void fps_body_ph(const float* __restrict__ xyz, int N, int M,
                                            int* __restrict__ fpsIdx, float* __restrict__ node1,
                                            float* __restrict__ distSv, int* __restrict__ lastSv,
                                            int b, char* smem) {
  #pragma clang fp contract(off)
  float4* sp4 = (float4*)smem;
  int*    fidx = (int*)(smem + 32768);
  float4* wvc  = (float4*)(smem + 32768 + 2048);
  int*    wis  = (int*)(smem + 32768 + 2048 + 128);
  int tid = threadIdx.x;
  int lane = tid & 63, w = tid >> 6;
  int HALF = M >> 1;
  const float* xb = xyz + (long)b * 3 * N;
  for (int n = tid; n < N; n += 256) {
    sp4[((n & 7) << 8) | (n >> 3)] = make_float4(xb[n], xb[N + n], xb[2 * N + n], 0.f);
  }
  if (PHASE == 1) {
    for (int e = tid; e < HALF; e += 256) fidx[e] = fpsIdx[(long)b * M + e];
  }
  __syncthreads();
  float4 pt[8];
  #pragma unroll
  for (int i = 0; i < 8; ++i) pt[i] = sp4[(i << 8) | tid];
  float dist[8];
  int last;
  float lx, ly, lz;
  if (PHASE == 0) {
    #pragma unroll
    for (int i = 0; i < 8; ++i) dist[i] = 1e10f;
    last = 0;
    float4 l0 = sp4[0];
    lx = l0.x; ly = l0.y; lz = l0.z;
  } else {
    #pragma unroll
    for (int i = 0; i < 8; ++i) dist[i] = distSv[(long)b * 2048 + i * 256 + tid];
    last = lastSv[b];
    float4 lp = sp4[((last & 7) << 8) | (last >> 3)];
    lx = lp.x; ly = lp.y; lz = lp.z;
  }
  int base = tid * 8;
  int it0 = (PHASE == 0) ? 0 : HALF;
  int it1 = (PHASE == 0) ? HALF : M;
  for (int it = it0; it < it1; ++it) {
    int p = it & 1;
    if (tid == 0) fidx[it] = last;
    float best = -INFINITY; int bi = N;
    #pragma unroll
    for (int i = 0; i < 8; ++i) {
      float dx = pt[i].x - lx, dy = pt[i].y - ly, dz = pt[i].z - lz;
      float dx2 = dx * dx, dy2 = dy * dy, dz2 = dz * dz;
      float d = (dx2 + dy2) + dz2;
      float dn = dist[i];
      if (d < dn) dn = d;
      dist[i] = dn;
      if (dn > best) { best = dn; bi = base + i; }
    }
    float cx = pt[0].x, cy = pt[0].y, cz = pt[0].z;
    #pragma unroll
    for (int i = 1; i < 8; ++i) {
      bool c = (bi == base + i);
      cx = c ? pt[i].x : cx; cy = c ? pt[i].y : cy; cz = c ? pt[i].z : cz;
    }
    float gmax = wave_fmax(best);
    int cand = (best == gmax) ? bi : 0x7FFFFFFF;
    int wbi = wave_imin(cand);
    if (bi == wbi) { wvc[p * 4 + w] = make_float4(gmax, cx, cy, cz); wis[p * 4 + w] = wbi; }
    __syncthreads();
    float4 c0 = wvc[p * 4 + 0], c1 = wvc[p * 4 + 1], c2 = wvc[p * 4 + 2], c3 = wvc[p * 4 + 3];
    int i0 = wis[p * 4 + 0], i1 = wis[p * 4 + 1], i2 = wis[p * 4 + 2], i3 = wis[p * 4 + 3];
    float bv = c0.x; int bbi = i0; lx = c0.y; ly = c0.z; lz = c0.w;
    { bool c = (c1.x > bv) || (c1.x == bv && i1 < bbi);
      bv = c ? c1.x : bv; bbi = c ? i1 : bbi; lx = c ? c1.y : lx; ly = c ? c1.z : ly; lz = c ? c1.w : lz; }
    { bool c = (c2.x > bv) || (c2.x == bv && i2 < bbi);
      bv = c ? c2.x : bv; bbi = c ? i2 : bbi; lx = c ? c2.y : lx; ly = c ? c2.z : ly; lz = c ? c2.w : lz; }
    { bool c = (c3.x > bv) || (c3.x == bv && i3 < bbi);
      bv = c ? c3.x : bv; bbi = c ? i3 : bbi; lx = c ? c3.y : lx; ly = c ? c3.z : ly; lz = c ? c3.w : lz; }
    last = bbi;
  }
  if (PHASE == 0) {
    for (int e = tid; e < HALF; e += 256) fpsIdx[(long)b * M + e] = fidx[e];
    #pragma unroll
    for (int i = 0; i < 8; ++i) distSv[(long)b * 2048 + i * 256 + tid] = dist[i];
    if (tid == 0) lastSv[b] = last;
  } else {
    for (int e = tid; e < M; e += 256) fpsIdx[(long)b * M + e] = fidx[e];
    for (int e = tid; e < 3 * M; e += 256) {
      int c = e / M, i = e % M;
      int src = fidx[i];
      float4 ptc = sp4[((src & 7) << 8) | (src >> 3)];
      node1[(long)b * 3 * M + e] = (c == 0) ? ptc.x : (c == 1) ? ptc.y : ptc.z;
    }
  }
}

// ---------------- fused {fps-half + knn + gemmPS}, 1D grid, fps first (R9) ----------------
template <int PHASE>
__global__ void knnfpsgemm_kernel(const float* __restrict__ Q, int qStrideB,
                                  const float* __restrict__ Xc, int cStrideB,
                                  int C, int Mq, int N, int k, int* __restrict__ idxOut,
                                  const float* __restrict__ W, int ldw, int O,
                                  float* __restrict__ Pt, float* __restrict__ St,
                                  const float* __restrict__ xyz, int Mf,
                                  int* __restrict__ fpsIdx, float* __restrict__ node1,
                                  float* __restrict__ distSv, int* __restrict__ lastSv,
                                  int nQblk, int nGblk, int nB) {
  __shared__ __align__(16) char smem[32768 + 2048 + 128 + 32];
  int bid = blockIdx.x;
  if (bid < nB) {
    __builtin_amdgcn_s_setprio(1);
    fps_body_ph<PHASE>(xyz, N, Mf, fpsIdx, node1, distSv, lastSv, bid, smem);
    __builtin_amdgcn_s_setprio(0);
  } else if (bid < nB + nB * nQblk) {
    int e = bid - nB;
    knn4_body<8>(Q, qStrideB, Xc, cStrideB, C, Mq, N, k, idxOut,
                 e / nQblk, (e % nQblk) * 4, smem);
  } else {
    int e = bid - nB - nB * nQblk;
    gemmPS_body(Xc, cStrideB, C, N, W, ldw, O, Pt, St,
                e / nGblk, (e % nGblk) * 64, 0, smem);
  }
}

// ---------------- fused {ecfinish2 + agg-knn}, striped (agg every 5th bid) ----------------
// ecfinish2: memory-gather-bound; agg-knn: VALU-latency-bound -> complementary mix per CU.
// agg writes a SEPARATE idxAgg buffer (idxK is concurrently read by ecfinish2).
__global__ void ecfagg_kernel(const float* __restrict__ Pt, const float* __restrict__ St,
                              const int* __restrict__ idxS2, int k2, int O2, int Np2,
                              const float* __restrict__ g2, const float* __restrict__ b2,
                              float* __restrict__ out2, long oStrideB2,
                              const float* __restrict__ Qn, int qStrideB,
                              const float* __restrict__ Xc, int cStrideB,
                              int Cq, int Mq, int Nc, int kq, int* __restrict__ idxAgg,
                              int nQblk, int nEperB) {
  __shared__ __align__(16) char smem[32768];
  int bid = blockIdx.x;
  if (bid % 5 == 0) {
    int a = bid / 5;                       // [0, 1024)
    knn4_body<8>(Qn, qStrideB, Xc, cStrideB, Cq, Mq, Nc, kq, idxAgg,
                 a / nQblk, (a % nQblk) * 4, smem);
  } else {
    int e = bid - bid / 5 - 1;             // [0, 4096) sequential
    ecfinish_body64(Pt, St, idxS2, k2, O2, Np2, g2, b2, out2, oStrideB2,
                    e / nEperB, e % nEperB);
  }
}

// ---------------- fused {gemm_colmaxA + xmfill}, striped (xmfill every 3rd bid) ----------------
__global__ void colmaxxm_kernel(const float* __restrict__ X, int xStrideB, int C, int Np,
                                const float* __restrict__ W, int ldw, int O,
                                const float* __restrict__ g, const float* __restrict__ bb,
                                float* __restrict__ partial, int nNT, int nOT,
                                const float* __restrict__ xt1, int N,
                                const int* __restrict__ fpsI, const int* __restrict__ idxA,
                                int kq, int M, float* __restrict__ xm) {
  __shared__ __align__(16) char smem[2 * 4160];
  int bid = blockIdx.x;
  if (bid % 3 == 0) {
    xmfill_body(xt1, N, fpsI, idxA, kq, M, xm, bid / 3);       // [0, 2048)
  } else {
    int e = bid - bid / 3 - 1;                                  // [0, 4096)
    int per = nNT * nOT;
    int b = e / per, r = e % per;
    int nt = r % nNT, ot = r / nNT;
    gemm_colmax_body(X, xStrideB, C, Np, W, ldw, O, g, bb, partial,
                     b, nt * 64, ot * 64, nt, nNT, smem);
  }
}

// ---------------- fused {knn<2> + gemmPS} for stages 3/4 (all blocks co-resident) --------
__global__ void knngemm_kernel(const float* __restrict__ Xin, int xStrideB,
                               int C, int Mq, int N, int k, int* __restrict__ idxOut,
                               const float* __restrict__ W, int ldw, int O,
                               float* __restrict__ Pt, float* __restrict__ St,
                               int nQblk, int nGn, int nGo, int nB) {
  __shared__ __align__(16) char smem[3 * 4160];
  int bid = blockIdx.x;
  if (bid < nB * nQblk) {
    knn4_body<2>(Xin, xStrideB, Xin, xStrideB, C, Mq, N, k, idxOut,
                 bid / nQblk, (bid % nQblk) * 4, smem);
  } else {
    int e = bid - nB * nQblk;
    int per = nGn * nGo;
    int b = e / per, r = e % per;
    int nt = r % nGn, ot = r / nGn;
    gemmPS_body(Xin, xStrideB, C, N, W, ldw, O, Pt, St, b, nt * 64, ot * 64, smem);
  }
}

// ---------------- head: fused colmax_finish + 3-layer MLP ----------------
__global__ void head_kernel(const float* __restrict__ partA, int NTa,
                            const float* __restrict__ partB, int NTb,
                            const float* __restrict__ Wl1, const float* __restrict__ g6, const float* __restrict__ b6,
                            const float* __restrict__ Wl2, const float* __restrict__ bl2,
                            const float* __restrict__ g7, const float* __restrict__ b7,
                            const float* __restrict__ Wl3, const float* __restrict__ bl3,
                            float* __restrict__ logits) {
  __shared__ float v[2048];
  __shared__ float h1[512];
  __shared__ float h2[256];
  int b = blockIdx.x, tid = threadIdx.x;
  for (int o = tid; o < 1024; o += 256) {
    float m = -INFINITY;
    for (int t = 0; t < NTa; ++t) m = fmaxf(m, partA[((long)b * NTa + t) * 1024 + o]);
    v[o] = m;
    float m2 = -INFINITY;
    for (int t = 0; t < NTb; ++t) m2 = fmaxf(m2, partB[((long)b * NTb + t) * 1024 + o]);
    v[1024 + o] = m2;
  }
  __syncthreads();
  for (int o = tid; o < 512; o += 256) {
    const float* wr = Wl1 + (long)o * 2048;
    float s = 0.f;
    for (int c = 0; c < 2048; c += 4) {
      float4 w4 = *(const float4*)(wr + c);
      s = fmaf(w4.x, v[c], s); s = fmaf(w4.y, v[c + 1], s);
      s = fmaf(w4.z, v[c + 2], s); s = fmaf(w4.w, v[c + 3], s);
    }
    float h = s * (g6[o] * BN_SCALE) + b6[o];
    h1[o] = h >= 0.f ? h : 0.2f * h;
  }
  __syncthreads();
  for (int o = tid; o < 256; o += 256) {
    const float* wr = Wl2 + (long)o * 512;
    float s = 0.f;
    for (int c = 0; c < 512; c += 4) {
      float4 w4 = *(const float4*)(wr + c);
      s = fmaf(w4.x, h1[c], s); s = fmaf(w4.y, h1[c + 1], s);
      s = fmaf(w4.z, h1[c + 2], s); s = fmaf(w4.w, h1[c + 3], s);
    }
    s += bl2[o];
    float h = s * (g7[o] * BN_SCALE) + b7[o];
    h2[o] = h >= 0.f ? h : 0.2f * h;
  }
  __syncthreads();
  if (tid < 40) {
    const float* wr = Wl3 + (long)tid * 256;
    float s = 0.f;
    for (int c = 0; c < 256; ++c) s = fmaf(wr[c], h2[c], s);
    logits[(long)b * 40 + tid] = s + bl3[tid];
  }
}

extern "C" void kernel_launch(void* const* d_in, const int* in_sizes, int n_in,
                              void* d_out, int out_size, void* d_ws, size_t ws_size,
                              hipStream_t stream) {
  const float* x   = (const float*)d_in[0];
  const float* W1  = (const float*)d_in[1];
  const float* g1  = (const float*)d_in[2];
  const float* b1  = (const float*)d_in[3];
  const float* W2  = (const float*)d_in[4];
  const float* g2  = (const float*)d_in[5];
  const float* b2  = (const float*)d_in[6];
  const float* W2m = (const float*)d_in[7];
  const float* g2m = (const float*)d_in[8];
  const float* b2m = (const float*)d_in[9];
  const float* W3  = (const float*)d_in[10];
  const float* g3  = (const float*)d_in[11];
  const float* b3  = (const float*)d_in[12];
  const float* W4  = (const float*)d_in[13];
  const float* g4  = (const float*)d_in[14];
  const float* b4  = (const float*)d_in[15];
  const float* W5  = (const float*)d_in[16];
  const float* g5  = (const float*)d_in[17];
  const float* b5  = (const float*)d_in[18];
  const float* Wl1 = (const float*)d_in[19];
  const float* g6  = (const float*)d_in[20];
  const float* b6  = (const float*)d_in[21];
  const float* Wl2 = (const float*)d_in[22];
  const float* bl2 = (const float*)d_in[23];
  const float* g7  = (const float*)d_in[24];
  const float* b7  = (const float*)d_in[25];
  const float* Wl3 = (const float*)d_in[26];
  const float* bl3 = (const float*)d_in[27];
  float* outF = (float*)d_out;

  const int B = 8, N = 2048, K = 20, M = 512, K2 = 10;

  float* ws    = (float*)d_ws;
  float* xt1   = ws;                               // (B,128,N)
  float* xm    = xt1 + (size_t)B * 128 * N;        // (B,256,M)
  float* xc    = xm  + (size_t)B * 256 * M;        // (B,512,M)
  float* Pt    = xc  + (size_t)B * 512 * M;        // max(B*N*64, B*M*256)
  float* St    = Pt  + (size_t)B * N * 64;
  float* partA = St  + (size_t)B * N * 64;         // (B,32,1024)
  float* partB = partA + (size_t)B * 32 * 1024;    // (B,8,1024)
  int*   idxK  = (int*)(partB + (size_t)B * 8 * 1024);  // (B,N,K)
  int*   fpsI  = idxK + (size_t)B * N * K;         // (B,M)
  float* fpsDist = (float*)(fpsI + (size_t)B * M); // (B,2048) fps checkpoint dists
  int*   fpsLast = (int*)(fpsDist + (size_t)B * 2048);  // (B)
  int*   idxAgg  = fpsLast + 64;                   // (B,M,K) aggregate-knn indices

  float* logits = outF;        // (B,40)
  float* node1  = outF + 320;  // (B,3,M)

  dim3 t256(256);
  const int nQblk = N / 4;     // 512 knn query-blocks per batch (N-point knn)
  const int nGblk = N / 64;    // 32 gemmPS n-tiles per batch (stage 1/2)
  const int nFused = B + B * nQblk + B * nGblk;
  const int nQa = M / 4;       // 128 agg/stage3/4 knn query-blocks per batch

  // ---- stage 1 FUSED: fps phase-0 + knn(xyz) + gemmPS1 (all depend only on x)
  knnfpsgemm_kernel<0><<<dim3(nFused), t256, 0, stream>>>(
      x, 3 * N, x, 3 * N, 3, N, N, K, idxK,
      W1, 6, 64, Pt, St,
      x, M, fpsI, node1, fpsDist, fpsLast, nQblk, nGblk, B);
  ecfinish_kernel<<<dim3(N / 4, B), dim3(64, 4), 0, stream>>>(Pt, St, idxK, K, 64, N, g1, b1, xt1, (long)128 * N);

  // ---- stage 2 FUSED: fps phase-1 + knn(x1) + gemmPS2
  knnfpsgemm_kernel<1><<<dim3(nFused), t256, 0, stream>>>(
      xt1, 128 * N, xt1, 128 * N, 64, N, N, K, idxK,
      W2, 128, 64, Pt, St,
      x, M, fpsI, node1, fpsDist, fpsLast, nQblk, nGblk, B);

  // ---- FUSED: ecfinish2 (gather-bound) + aggregate-knn (VALU-latency-bound), striped
  ecfagg_kernel<<<dim3(B * nQa + B * (N / 4)), t256, 0, stream>>>(
      Pt, St, idxK, K, 64, N, g2, b2, xt1 + (size_t)64 * N, (long)128 * N,
      node1, 3 * M, x, 3 * N, 3, M, N, K, idxAgg, nQa, N / 4);

  // ---- FUSED: gemm_colmaxA (VALU-bound) + xmfill (gather-bound), striped
  colmaxxm_kernel<<<dim3((B * 128 * M) / 256 + B * 32 * 16), t256, 0, stream>>>(
      xt1, 128 * N, 128, N, W2m, 128, 1024, g2m, b2m, partA, 32, 16,
      xt1, N, fpsI, idxAgg, K, M, xm);

  // ---- stage 3 FUSED: knn(xm) + gemmPS3 (both read xm; all blocks co-resident)
  knngemm_kernel<<<dim3(B * nQa + B * (M / 64) * (256 / 64)), t256, 0, stream>>>(
      xm, 256 * M, 256, M, M, K2, idxK, W3, 512, 256, Pt, St, nQa, M / 64, 256 / 64, B);
  ecfinish_kernel<<<dim3(M, B), dim3(256, 1), 0, stream>>>(Pt, St, idxK, K2, 256, M, g3, b3, xc, (long)512 * M);

  // ---- stage 4 FUSED: knn(x3) + gemmPS4
  knngemm_kernel<<<dim3(B * nQa + B * (M / 64) * (256 / 64)), t256, 0, stream>>>(
      xc, 512 * M, 256, M, M, K2, idxK, W4, 512, 256, Pt, St, nQa, M / 64, 256 / 64, B);
  ecfinish_kernel<<<dim3(M, B), dim3(256, 1), 0, stream>>>(Pt, St, idxK, K2, 256, M, g4, b4,
                                                           xc + (size_t)256 * M, (long)512 * M);

  // ---- vs partials
  gemm_colmax_kernel<<<dim3(M / 64, 1024 / 64, B), t256, 0, stream>>>(xc, 512 * M, 512, M, W5, 512, 1024,
                                                                      g5, b5, partB);

  // ---- head (fused colmax_finish + MLP)
  head_kernel<<<dim3(B), t256, 0, stream>>>(partA, N / 64, partB, M / 64,
                                            Wl1, g6, b6, Wl2, bl2, g7, b7, Wl3, bl3, logits);
}